// Round 8
// baseline (1139.175 us; speedup 1.0000x reference)
//
#include <hip/hip_runtime.h>
#include <math.h>

typedef unsigned int U32;
typedef unsigned long long U64;

#define NBOX   90000
#define NPIX   10000
#define KDIM   1024
#define CBOT   512
#define PRE_N  6000
#define POST_N 300
#define NWORD  94      // ceil(6000/64)

// ---------------- workspace layout (byte offsets, all 16B aligned) ----------
#define OFF_H       0ULL          // 10000*512*4   = 20480000
#define OFF_BOXES   20480000ULL   // 90000*4*4     = 1440000
#define OFF_KEYS    21920000ULL   // 90000*4       = 360000
#define OFF_MASKT   22280000ULL   // maskR: 6000*94*8 = 4512000 (region 4524032)
#define OFF_SEL     26804032ULL   // 6000*8        = 48000
#define OFF_SBOX    26852032ULL   // 6000*4*4      = 96000
#define OFF_VALIDW  26948032ULL   // 94*8 -> 768
#define OFF_KEEPW   26948800ULL   // 768
#define OFF_HIST    26949568ULL   // 256*4 -> 1024
#define OFF_CNT     26950592ULL   // 64*4  -> 256
#define OFF_TIE     26950848ULL   // 4096*4 = 16384
#define WS_NEED     26967232ULL

// cnt[] slots: 0=prefix/T  1=target_remaining(->need_ties)  2=c_gt  8=n_gt atomic  9=n_tie atomic

// ============================================================================
// K1: h = relu(feats @ W_b + b_b)   fp32, 128x64 tile, BK=16
// Also zero-inits hist/cnt/validw (block (0,0) only).
// ============================================================================
__global__ __launch_bounds__(256) void k_gemm1(
    const float* __restrict__ A, const float* __restrict__ W,
    const float* __restrict__ bias, float* __restrict__ H,
    U32* __restrict__ hist, U32* __restrict__ cnt, U32* __restrict__ validw32)
{
  int t = threadIdx.x;
  if (blockIdx.x == 0 && blockIdx.y == 0) {
    hist[t] = 0;
    if (t < 64)  cnt[t] = (t == 1) ? (U32)PRE_N : 0u;
    if (t < 188) validw32[t] = 0;
  }
  __shared__ float As[16][132];   // [k][m], +4 pad keeps 16B alignment
  __shared__ float Bs[16][64];    // [k][n]
  int m0 = blockIdx.y * 128, n0 = blockIdx.x * 64;
  int tm = t >> 4, tn = t & 15;
  int ar = t >> 2, ac = (t & 3) << 2;
  int bk = t >> 4, bc = (t & 15) << 2;
  float acc[8][4];
#pragma unroll
  for (int i = 0; i < 8; ++i)
#pragma unroll
    for (int j = 0; j < 4; ++j) acc[i][j] = 0.f;

  for (int k0 = 0; k0 < KDIM; k0 += 16) {
    int r0 = m0 + ar, r1 = r0 + 64;
    float4 a0 = make_float4(0.f,0.f,0.f,0.f), a1 = a0;
    if (r0 < NPIX) a0 = *(const float4*)&A[(size_t)r0 * KDIM + k0 + ac];
    if (r1 < NPIX) a1 = *(const float4*)&A[(size_t)r1 * KDIM + k0 + ac];
    float4 b = *(const float4*)&W[(size_t)(k0 + bk) * CBOT + n0 + bc];
    __syncthreads();
    As[ac+0][ar] = a0.x; As[ac+1][ar] = a0.y; As[ac+2][ar] = a0.z; As[ac+3][ar] = a0.w;
    As[ac+0][ar+64] = a1.x; As[ac+1][ar+64] = a1.y; As[ac+2][ar+64] = a1.z; As[ac+3][ar+64] = a1.w;
    *(float4*)&Bs[bk][bc] = b;
    __syncthreads();
#pragma unroll
    for (int kk = 0; kk < 16; ++kk) {
      float4 av0 = *(float4*)&As[kk][tm*8];
      float4 av1 = *(float4*)&As[kk][tm*8+4];
      float4 bv  = *(float4*)&Bs[kk][tn*4];
      float am[8] = {av0.x,av0.y,av0.z,av0.w,av1.x,av1.y,av1.z,av1.w};
      float bm[4] = {bv.x,bv.y,bv.z,bv.w};
#pragma unroll
      for (int i = 0; i < 8; ++i)
#pragma unroll
        for (int j = 0; j < 4; ++j)
          acc[i][j] = fmaf(am[i], bm[j], acc[i][j]);
    }
  }
  float4 bb = *(const float4*)&bias[n0 + tn*4];
  float bm[4] = {bb.x, bb.y, bb.z, bb.w};
#pragma unroll
  for (int i = 0; i < 8; ++i) {
    int r = m0 + tm*8 + i;
    if (r < NPIX) {
      float4 o;
      o.x = fmaxf(acc[i][0] + bm[0], 0.f);
      o.y = fmaxf(acc[i][1] + bm[1], 0.f);
      o.z = fmaxf(acc[i][2] + bm[2], 0.f);
      o.w = fmaxf(acc[i][3] + bm[3], 0.f);
      *(float4*)&H[(size_t)r * CBOT + n0 + tn*4] = o;
    }
  }
}

// ============================================================================
// K2: cls = sigmoid(h@W_cls+b_cls), reg = h@W_reg+b_reg  (4 pixels / block)
// ============================================================================
__global__ __launch_bounds__(256) void k_heads(
    const float* __restrict__ H, const float* __restrict__ Wc,
    const float* __restrict__ bc, const float* __restrict__ Wr,
    const float* __restrict__ br, float* __restrict__ outCls,
    float* __restrict__ outReg)
{
  __shared__ float hs[4][516];
  int t = threadIdx.x;
  int p0 = blockIdx.x * 4;
  for (int q = t; q < 512; q += 256) {
    int row = q >> 7, off = (q & 127) << 2;
    *(float4*)&hs[row][off] = *(const float4*)&H[(size_t)(p0 + row) * CBOT + off];
  }
  __syncthreads();
  if (t < 180) {
    int pl = t / 45, c = t % 45;
    const float* wp; int stride; float bval;
    if (c < 9) { wp = Wc + c;       stride = 9;  bval = bc[c]; }
    else       { wp = Wr + (c - 9); stride = 36; bval = br[c - 9]; }
    float s = 0.f;
    const float* hrow = hs[pl];
    for (int k = 0; k < CBOT; k += 4) {
      float4 hv = *(const float4*)&hrow[k];
      s = fmaf(hv.x, wp[(size_t)(k+0)*stride], s);
      s = fmaf(hv.y, wp[(size_t)(k+1)*stride], s);
      s = fmaf(hv.z, wp[(size_t)(k+2)*stride], s);
      s = fmaf(hv.w, wp[(size_t)(k+3)*stride], s);
    }
    s += bval;
    int p = p0 + pl;
    if (c < 9) outCls[(size_t)p*9 + c] = 1.f / (1.f + expf(-s));
    else       outReg[(size_t)p*36 + (c - 9)] = s;
  }
}

// ============================================================================
// K3: decode boxes, size filter, sortable keys, level-0 histogram
// ============================================================================
__global__ __launch_bounds__(256) void k_decode(
    const float* __restrict__ outCls, const float* __restrict__ outReg,
    const float* __restrict__ ancs, float* __restrict__ boxes,
    U32* __restrict__ keys, U32* __restrict__ hist)
{
  __shared__ U32 lh[256];
  int t = threadIdx.x;
  int tid = blockIdx.x * 256 + t;
  lh[t] = 0;
  __syncthreads();
  if (tid < NBOX) {
    float sc = outCls[tid];
    float4 of = *(const float4*)&outReg[(size_t)tid*4];
    float4 an = *(const float4*)&ancs[(size_t)tid*4];
    float cx = an.x + of.x * an.z;
    float cy = an.y + of.y * an.w;
    float ww = an.z * expf(of.z);
    float hh = an.w * expf(of.w);
    float x1 = fminf(fmaxf(cx - ww * 0.5f, 0.f), 1.f);
    float y1 = fminf(fmaxf(cy - hh * 0.5f, 0.f), 1.f);
    float x2 = fminf(fmaxf(cx + ww * 0.5f, 0.f), 1.f);
    float y2 = fminf(fmaxf(cy + hh * 0.5f, 0.f), 1.f);
    bool ok = ((x2 - x1) * 100.f >= 1.f) && ((y2 - y1) * 100.f >= 1.f);
    float msc = ok ? sc : -1.f;
    U32 u = __float_as_uint(msc);
    U32 key = (u & 0x80000000u) ? ~u : (u | 0x80000000u);
    keys[tid] = key;
    *(float4*)&boxes[(size_t)tid*4] = make_float4(x1, y1, x2, y2);
    atomicAdd(&lh[key >> 24], 1u);
  }
  __syncthreads();
  if (lh[t]) atomicAdd(&hist[t], lh[t]);
}

// ============================================================================
// K4: radix-select scan step (one per level). Picks digit, updates prefix /
// remaining target / count-above, zeroes hist for next level.
// ============================================================================
__global__ __launch_bounds__(256) void k_scan(
    U32* __restrict__ hist, U32* __restrict__ cnt, int level)
{
  __shared__ U32 lh[256];
  int t = threadIdx.x;
  lh[t] = hist[t];
  __syncthreads();
  if (t == 0) {
    U32 target = cnt[1];
    U32 cum = 0;
    int d = 255;
    while (d > 0) {
      U32 hh = lh[d];
      if (cum + hh >= target) break;
      cum += hh; --d;
    }
    cnt[0] |= ((U32)d) << (24 - 8*level);
    cnt[1] = target - cum;
    cnt[2] += cum;
  }
  __syncthreads();
  hist[t] = 0;
}

// ============================================================================
// K5: filtered histogram for levels 1..3
// ============================================================================
__global__ __launch_bounds__(256) void k_hist(
    const U32* __restrict__ keys, U32* __restrict__ hist,
    const U32* __restrict__ cnt, int level)
{
  __shared__ U32 lh[256];
  int t = threadIdx.x;
  int tid = blockIdx.x * 256 + t;
  lh[t] = 0;
  __syncthreads();
  if (tid < NBOX) {
    U32 k = keys[tid];
    U32 prefix = cnt[0];
    int shift = 32 - 8*level;
    if ((k >> shift) == (prefix >> shift)) {
      U32 bin = (k >> (24 - 8*level)) & 0xFFu;
      atomicAdd(&lh[bin], 1u);
    }
  }
  __syncthreads();
  if (lh[t]) atomicAdd(&hist[t], lh[t]);
}

// ============================================================================
// K6: compact: keys > T -> sel (unordered; rank pass sorts later);
//     keys == T -> tie buffer.
// ============================================================================
__global__ __launch_bounds__(256) void k_compact(
    const U32* __restrict__ keys, U32* __restrict__ cnt,
    U64* __restrict__ sel, U32* __restrict__ tiebuf)
{
  int tid = blockIdx.x * 256 + threadIdx.x;
  if (tid >= NBOX) return;
  U32 k = keys[tid];
  U32 T = cnt[0];
  if (k > T) {
    U32 p = atomicAdd(&cnt[8], 1u);
    sel[p] = ((U64)k << 32) | (U64)(0xFFFFFFFFu - (U32)tid);
  } else if (k == T) {
    U32 p = atomicAdd(&cnt[9], 1u);
    if (p < 4096) tiebuf[p] = (U32)tid;
  }
}

// ============================================================================
// K7: resolve ==T ties by smallest index (stable top_k semantics)
// ============================================================================
__global__ __launch_bounds__(256) void k_ties(
    U32* __restrict__ cnt, const U32* __restrict__ tiebuf, U64* __restrict__ sel)
{
  __shared__ U32 tb[4096];
  int t = threadIdx.x;
  U32 m = cnt[9]; if (m > 4096u) m = 4096u;
  U32 need = cnt[1];
  U32 cgt  = cnt[2];
  U32 T    = cnt[0];
  for (U32 j = t; j < m; j += 256) tb[j] = tiebuf[j];
  __syncthreads();
  for (U32 x = t; x < m; x += 256) {
    U32 my = tb[x];
    U32 r = 0;
    for (U32 j = 0; j < m; ++j) r += (tb[j] < my) ? 1u : 0u;
    if (r < need) sel[cgt + r] = ((U64)T << 32) | (U64)(0xFFFFFFFFu - my);
  }
}

// ============================================================================
// K8: exact rank of each selected element (score desc, idx asc) -> sorted
// boxes + packed valid bits. 36M u64 compares, LDS-staged. Order-invariant
// wrt sel's (atomic-nondeterministic) storage order.
// ============================================================================
__global__ __launch_bounds__(256) void k_rank(
    const U64* __restrict__ sel, const float* __restrict__ boxes,
    float* __restrict__ sboxes, U64* __restrict__ validw)
{
  __shared__ U64 ss[PRE_N];
  int t = threadIdx.x;
  for (int j = t; j < PRE_N; j += 256) ss[j] = sel[j];
  __syncthreads();
  int i = blockIdx.x * 256 + t;
  if (i >= PRE_N) return;
  U64 C = ss[i];
  int r = 0;
  for (int j = 0; j < PRE_N; ++j) r += (ss[j] > C) ? 1 : 0;
  U32 key = (U32)(C >> 32);
  U32 idx = 0xFFFFFFFFu - (U32)(C & 0xFFFFFFFFull);
  *(float4*)&sboxes[(size_t)r*4] = *(const float4*)&boxes[(size_t)idx*4];
  if (key & 0x80000000u)
    atomicOr(&validw[r >> 6], 1ull << (r & 63));
}

// ============================================================================
// K9: IoU > 0.7 bitmask, ROW-major: maskR[row*94 + cw] bit x =
//     iou(row, box cw*64+x) > thr. Lower-triangle blocks (cw < rg) are
//     ZERO-filled (those bits cover already-decided rows; zeroing keeps the
//     NMS OR branch-free and all reads deterministic).
// ============================================================================
__global__ __launch_bounds__(256) void k_mask(
    const float* __restrict__ sboxes, U64* __restrict__ maskR)
{
  int cw = blockIdx.x, rg = blockIdx.y;
  int t = threadIdx.x;
  if (cw < rg) {                             // zero-fill, no IoU needed
    if (t < 64) {
      int row = rg * 64 + t;
      if (row < PRE_N) maskR[(size_t)row * NWORD + cw] = 0ull;
    }
    return;
  }
  int lane = t & 63, wv = t >> 6;
  int col = cw * 64 + lane;
  int cc = (col < PRE_N) ? col : (PRE_N - 1);
  float4 cb = *(const float4*)&sboxes[(size_t)cc*4];
  float areaC = (cb.z - cb.x) * (cb.w - cb.y);
  bool colok = (col < PRE_N);
  for (int rr = wv; rr < 64; rr += 4) {
    int row = rg * 64 + rr;
    if (row < PRE_N) {
      float4 rb = *(const float4*)&sboxes[(size_t)row*4];
      float areaR = (rb.z - rb.x) * (rb.w - rb.y);
      float ix1 = fmaxf(rb.x, cb.x), iy1 = fmaxf(rb.y, cb.y);
      float ix2 = fminf(rb.z, cb.z), iy2 = fminf(rb.w, cb.w);
      float inter = fmaxf(ix2 - ix1, 0.f) * fmaxf(iy2 - iy1, 0.f);
      float uni = areaR + areaC - inter;
      float iou = inter / fmaxf(uni, 1e-9f);
      U64 word = __ballot(colok && (iou > 0.7f));
      if (lane == 0) maskR[(size_t)row * NWORD + cw] = word;
    }
  }
}

// ============================================================================
// K10: sequential NMS — register-resident suppression vector, zero memory on
// the serial chain. Lane l (<47) owns sup/valid/keep words 2l,2l+1. Per row i
// (ascending, exact reference order): owning lane tests valid&!sup bit i,
// __ballot broadcasts the decision (no shfl chain); if kept, every lane ORs
// its 2 words of mask row i (prefetched 16 rows ahead into static-index
// registers; 64 VGPRs, fits the ~128 budget — R7 lesson: oversized buffers
// spill and serialize). Loads are unconditional & L2-hot (maskR = 4.5 MB).
// ============================================================================
__global__ __launch_bounds__(64, 1) void k_nms(
    const U64* __restrict__ maskR, const U64* __restrict__ validw,
    U64* __restrict__ keepw)
{
  int l = threadIdx.x;
  int wo = (l < 47) ? (l << 1) : 0;          // pair of words this lane owns
  const U64* mrow = maskR + wo;
  U64 vx = validw[wo], vy = validw[wo + 1];
  U64 sx = 0, sy = 0, kx = 0, ky = 0;
  U64 mx[16], my[16];
#pragma unroll
  for (int q = 0; q < 16; ++q) {             // prologue: rows 0..15
    ulonglong2 tt = *(const ulonglong2*)(mrow + (size_t)q * NWORD);
    mx[q] = tt.x; my[q] = tt.y;
  }
  for (int ib = 0; ib < PRE_N; ib += 16) {   // 375 iterations exactly
#pragma unroll
    for (int q = 0; q < 16; ++q) {
      int i = ib + q;
      int wi = i >> 6;                       // uniform word index
      U64 bit = 1ull << (i & 63);
      U64 ms = (wi & 1) ? sy : sx;
      U64 mv = (wi & 1) ? vy : vx;
      bool tst = (l == (wi >> 1)) && ((mv & bit) != 0ull) && ((ms & bit) == 0ull);
      if (__ballot(tst) != 0ull) {           // uniform: row i kept
        sx |= mx[q]; sy |= my[q];
        if (l == (wi >> 1)) { if (wi & 1) ky |= bit; else kx |= bit; }
      }
      int pr = i + 16;                       // prefetch row i+16 (clamped)
      if (pr > PRE_N - 1) pr = PRE_N - 1;
      ulonglong2 tt = *(const ulonglong2*)(mrow + (size_t)pr * NWORD);
      mx[q] = tt.x; my[q] = tt.y;
    }
  }
  if (l < 47) { keepw[l << 1] = kx; keepw[(l << 1) + 1] = ky; }
}

// ============================================================================
// K11: proposals: prefix-popcount ranks, first 300 kept boxes, zeros elsewhere
// ============================================================================
__global__ __launch_bounds__(256) void k_out(
    const U64* __restrict__ keepw, const float* __restrict__ sboxes,
    float* __restrict__ prop)
{
  __shared__ U64 kw[NWORD];
  __shared__ U32 pre[NWORD + 1];
  int t = threadIdx.x;
  if (t < NWORD) kw[t] = keepw[t];
  __syncthreads();
  if (t == 0) {
    U32 s = 0;
    for (int w = 0; w < NWORD; ++w) { pre[w] = s; s += (U32)__popcll(kw[w]); }
    pre[NWORD] = s;
  }
  for (int x = t; x < POST_N * 4; x += 256) prop[x] = 0.f;
  __syncthreads();
  for (int i = t; i < PRE_N; i += 256) {
    int w = i >> 6, b = i & 63;
    if ((kw[w] >> b) & 1ull) {
      U64 lowb = (b == 0) ? 0ull : (~0ull >> (64 - b));
      U32 r = pre[w] + (U32)__popcll(kw[w] & lowb);
      if (r < POST_N)
        *(float4*)&prop[(size_t)r*4] = *(const float4*)&sboxes[(size_t)i*4];
    }
  }
}

// ============================================================================
extern "C" void kernel_launch(void* const* d_in, const int* in_sizes, int n_in,
                              void* d_out, int out_size, void* d_ws, size_t ws_size,
                              hipStream_t stream)
{
  (void)in_sizes; (void)n_in; (void)out_size;
  if (ws_size < WS_NEED) return;   // scratch too small; bail safely

  const float* feats = (const float*)d_in[0];
  const float* ancs  = (const float*)d_in[1];
  const float* W_b   = (const float*)d_in[3];
  const float* b_b   = (const float*)d_in[4];
  const float* W_cls = (const float*)d_in[5];
  const float* b_cls = (const float*)d_in[6];
  const float* W_reg = (const float*)d_in[7];
  const float* b_reg = (const float*)d_in[8];

  float* out    = (float*)d_out;
  float* outCls = out;                 // 90000
  float* outReg = out + 90000;         // 360000
  float* prop   = out + 450000;        // 1200

  char* ws = (char*)d_ws;
  float* H      = (float*)(ws + OFF_H);
  float* boxes  = (float*)(ws + OFF_BOXES);
  U32*   keys   = (U32*)  (ws + OFF_KEYS);
  U64*   maskR  = (U64*)  (ws + OFF_MASKT);
  U64*   sel    = (U64*)  (ws + OFF_SEL);
  float* sboxes = (float*)(ws + OFF_SBOX);
  U64*   validw = (U64*)  (ws + OFF_VALIDW);
  U64*   keepw  = (U64*)  (ws + OFF_KEEPW);
  U32*   hist   = (U32*)  (ws + OFF_HIST);
  U32*   cnt    = (U32*)  (ws + OFF_CNT);
  U32*   tiebuf = (U32*)  (ws + OFF_TIE);

  k_gemm1<<<dim3(8, 79), dim3(256), 0, stream>>>(feats, W_b, b_b, H,
                                                 hist, cnt, (U32*)validw);
  k_heads<<<dim3(2500), dim3(256), 0, stream>>>(H, W_cls, b_cls, W_reg, b_reg,
                                                outCls, outReg);
  k_decode<<<dim3(352), dim3(256), 0, stream>>>(outCls, outReg, ancs,
                                                boxes, keys, hist);
  k_scan<<<dim3(1), dim3(256), 0, stream>>>(hist, cnt, 0);
  for (int lv = 1; lv <= 3; ++lv) {
    k_hist<<<dim3(352), dim3(256), 0, stream>>>(keys, hist, cnt, lv);
    k_scan<<<dim3(1), dim3(256), 0, stream>>>(hist, cnt, lv);
  }
  k_compact<<<dim3(352), dim3(256), 0, stream>>>(keys, cnt, sel, tiebuf);
  k_ties<<<dim3(1), dim3(256), 0, stream>>>(cnt, tiebuf, sel);
  k_rank<<<dim3(24), dim3(256), 0, stream>>>(sel, boxes, sboxes, validw);
  k_mask<<<dim3(94, 94), dim3(256), 0, stream>>>(sboxes, maskR);
  k_nms<<<dim3(1), dim3(64), 0, stream>>>(maskR, validw, keepw);
  k_out<<<dim3(1), dim3(256), 0, stream>>>(keepw, sboxes, prop);
}

// Round 9
// 692.959 us; speedup vs baseline: 1.6439x; 1.6439x over previous
//
#include <hip/hip_runtime.h>
#include <math.h>

typedef unsigned int U32;
typedef unsigned long long U64;

#define NBOX   90000
#define NPIX   10000
#define KDIM   1024
#define CBOT   512
#define PRE_N  6000
#define POST_N 300
#define NWORD  94      // ceil(6000/64)
#define MROWS  6016    // 94*64 rows allocated per column in maskT
#define NSLOTMAX 47    // max 128-row slots per chunk

// ---------------- workspace layout (byte offsets, all 16B aligned) ----------
#define OFF_H       0ULL          // 10000*512*4   = 20480000
#define OFF_BOXES   20480000ULL   // 90000*4*4     = 1440000
#define OFF_KEYS    21920000ULL   // 90000*4       = 360000
#define OFF_MASKT   22280000ULL   // 94*6016*8     = 4524032 (column-major)
#define OFF_SEL     26804032ULL   // 6000*8        = 48000
#define OFF_SBOX    26852032ULL   // 6000*4*4      = 96000
#define OFF_VALIDW  26948032ULL   // 94*8 -> 768
#define OFF_KEEPW   26948800ULL   // 768
#define OFF_HIST    26949568ULL   // 256*4 -> 1024
#define OFF_CNT     26950592ULL   // 64*4  -> 256
#define OFF_TIE     26950848ULL   // 4096*4 = 16384
#define WS_NEED     26967232ULL

// cnt[] slots: 0=prefix/T  1=target_remaining(->need_ties)  2=c_gt  8=n_gt atomic  9=n_tie atomic

// ============================================================================
// K1: h = relu(feats @ W_b + b_b)   fp32, 128x64 tile, BK=16
// Also zero-inits hist/cnt/validw (block (0,0) only).
// ============================================================================
__global__ __launch_bounds__(256) void k_gemm1(
    const float* __restrict__ A, const float* __restrict__ W,
    const float* __restrict__ bias, float* __restrict__ H,
    U32* __restrict__ hist, U32* __restrict__ cnt, U32* __restrict__ validw32)
{
  int t = threadIdx.x;
  if (blockIdx.x == 0 && blockIdx.y == 0) {
    hist[t] = 0;
    if (t < 64)  cnt[t] = (t == 1) ? (U32)PRE_N : 0u;
    if (t < 188) validw32[t] = 0;
  }
  __shared__ float As[16][132];   // [k][m], +4 pad keeps 16B alignment
  __shared__ float Bs[16][64];    // [k][n]
  int m0 = blockIdx.y * 128, n0 = blockIdx.x * 64;
  int tm = t >> 4, tn = t & 15;
  int ar = t >> 2, ac = (t & 3) << 2;
  int bk = t >> 4, bc = (t & 15) << 2;
  float acc[8][4];
#pragma unroll
  for (int i = 0; i < 8; ++i)
#pragma unroll
    for (int j = 0; j < 4; ++j) acc[i][j] = 0.f;

  for (int k0 = 0; k0 < KDIM; k0 += 16) {
    int r0 = m0 + ar, r1 = r0 + 64;
    float4 a0 = make_float4(0.f,0.f,0.f,0.f), a1 = a0;
    if (r0 < NPIX) a0 = *(const float4*)&A[(size_t)r0 * KDIM + k0 + ac];
    if (r1 < NPIX) a1 = *(const float4*)&A[(size_t)r1 * KDIM + k0 + ac];
    float4 b = *(const float4*)&W[(size_t)(k0 + bk) * CBOT + n0 + bc];
    __syncthreads();
    As[ac+0][ar] = a0.x; As[ac+1][ar] = a0.y; As[ac+2][ar] = a0.z; As[ac+3][ar] = a0.w;
    As[ac+0][ar+64] = a1.x; As[ac+1][ar+64] = a1.y; As[ac+2][ar+64] = a1.z; As[ac+3][ar+64] = a1.w;
    *(float4*)&Bs[bk][bc] = b;
    __syncthreads();
#pragma unroll
    for (int kk = 0; kk < 16; ++kk) {
      float4 av0 = *(float4*)&As[kk][tm*8];
      float4 av1 = *(float4*)&As[kk][tm*8+4];
      float4 bv  = *(float4*)&Bs[kk][tn*4];
      float am[8] = {av0.x,av0.y,av0.z,av0.w,av1.x,av1.y,av1.z,av1.w};
      float bm[4] = {bv.x,bv.y,bv.z,bv.w};
#pragma unroll
      for (int i = 0; i < 8; ++i)
#pragma unroll
        for (int j = 0; j < 4; ++j)
          acc[i][j] = fmaf(am[i], bm[j], acc[i][j]);
    }
  }
  float4 bb = *(const float4*)&bias[n0 + tn*4];
  float bm[4] = {bb.x, bb.y, bb.z, bb.w};
#pragma unroll
  for (int i = 0; i < 8; ++i) {
    int r = m0 + tm*8 + i;
    if (r < NPIX) {
      float4 o;
      o.x = fmaxf(acc[i][0] + bm[0], 0.f);
      o.y = fmaxf(acc[i][1] + bm[1], 0.f);
      o.z = fmaxf(acc[i][2] + bm[2], 0.f);
      o.w = fmaxf(acc[i][3] + bm[3], 0.f);
      *(float4*)&H[(size_t)r * CBOT + n0 + tn*4] = o;
    }
  }
}

// ============================================================================
// K2: cls = sigmoid(h@W_cls+b_cls), reg = h@W_reg+b_reg  (4 pixels / block)
// ============================================================================
__global__ __launch_bounds__(256) void k_heads(
    const float* __restrict__ H, const float* __restrict__ Wc,
    const float* __restrict__ bc, const float* __restrict__ Wr,
    const float* __restrict__ br, float* __restrict__ outCls,
    float* __restrict__ outReg)
{
  __shared__ float hs[4][516];
  int t = threadIdx.x;
  int p0 = blockIdx.x * 4;
  for (int q = t; q < 512; q += 256) {
    int row = q >> 7, off = (q & 127) << 2;
    *(float4*)&hs[row][off] = *(const float4*)&H[(size_t)(p0 + row) * CBOT + off];
  }
  __syncthreads();
  if (t < 180) {
    int pl = t / 45, c = t % 45;
    const float* wp; int stride; float bval;
    if (c < 9) { wp = Wc + c;       stride = 9;  bval = bc[c]; }
    else       { wp = Wr + (c - 9); stride = 36; bval = br[c - 9]; }
    float s = 0.f;
    const float* hrow = hs[pl];
    for (int k = 0; k < CBOT; k += 4) {
      float4 hv = *(const float4*)&hrow[k];
      s = fmaf(hv.x, wp[(size_t)(k+0)*stride], s);
      s = fmaf(hv.y, wp[(size_t)(k+1)*stride], s);
      s = fmaf(hv.z, wp[(size_t)(k+2)*stride], s);
      s = fmaf(hv.w, wp[(size_t)(k+3)*stride], s);
    }
    s += bval;
    int p = p0 + pl;
    if (c < 9) outCls[(size_t)p*9 + c] = 1.f / (1.f + expf(-s));
    else       outReg[(size_t)p*36 + (c - 9)] = s;
  }
}

// ============================================================================
// K3: decode boxes, size filter, sortable keys, level-0 histogram
// ============================================================================
__global__ __launch_bounds__(256) void k_decode(
    const float* __restrict__ outCls, const float* __restrict__ outReg,
    const float* __restrict__ ancs, float* __restrict__ boxes,
    U32* __restrict__ keys, U32* __restrict__ hist)
{
  __shared__ U32 lh[256];
  int t = threadIdx.x;
  int tid = blockIdx.x * 256 + t;
  lh[t] = 0;
  __syncthreads();
  if (tid < NBOX) {
    float sc = outCls[tid];
    float4 of = *(const float4*)&outReg[(size_t)tid*4];
    float4 an = *(const float4*)&ancs[(size_t)tid*4];
    float cx = an.x + of.x * an.z;
    float cy = an.y + of.y * an.w;
    float ww = an.z * expf(of.z);
    float hh = an.w * expf(of.w);
    float x1 = fminf(fmaxf(cx - ww * 0.5f, 0.f), 1.f);
    float y1 = fminf(fmaxf(cy - hh * 0.5f, 0.f), 1.f);
    float x2 = fminf(fmaxf(cx + ww * 0.5f, 0.f), 1.f);
    float y2 = fminf(fmaxf(cy + hh * 0.5f, 0.f), 1.f);
    bool ok = ((x2 - x1) * 100.f >= 1.f) && ((y2 - y1) * 100.f >= 1.f);
    float msc = ok ? sc : -1.f;
    U32 u = __float_as_uint(msc);
    U32 key = (u & 0x80000000u) ? ~u : (u | 0x80000000u);
    keys[tid] = key;
    *(float4*)&boxes[(size_t)tid*4] = make_float4(x1, y1, x2, y2);
    atomicAdd(&lh[key >> 24], 1u);
  }
  __syncthreads();
  if (lh[t]) atomicAdd(&hist[t], lh[t]);
}

// ============================================================================
// K4: radix-select scan step (one per level). Picks digit, updates prefix /
// remaining target / count-above, zeroes hist for next level.
// ============================================================================
__global__ __launch_bounds__(256) void k_scan(
    U32* __restrict__ hist, U32* __restrict__ cnt, int level)
{
  __shared__ U32 lh[256];
  int t = threadIdx.x;
  lh[t] = hist[t];
  __syncthreads();
  if (t == 0) {
    U32 target = cnt[1];
    U32 cum = 0;
    int d = 255;
    while (d > 0) {
      U32 hh = lh[d];
      if (cum + hh >= target) break;
      cum += hh; --d;
    }
    cnt[0] |= ((U32)d) << (24 - 8*level);
    cnt[1] = target - cum;
    cnt[2] += cum;
  }
  __syncthreads();
  hist[t] = 0;
}

// ============================================================================
// K5: filtered histogram for levels 1..3
// ============================================================================
__global__ __launch_bounds__(256) void k_hist(
    const U32* __restrict__ keys, U32* __restrict__ hist,
    const U32* __restrict__ cnt, int level)
{
  __shared__ U32 lh[256];
  int t = threadIdx.x;
  int tid = blockIdx.x * 256 + t;
  lh[t] = 0;
  __syncthreads();
  if (tid < NBOX) {
    U32 k = keys[tid];
    U32 prefix = cnt[0];
    int shift = 32 - 8*level;
    if ((k >> shift) == (prefix >> shift)) {
      U32 bin = (k >> (24 - 8*level)) & 0xFFu;
      atomicAdd(&lh[bin], 1u);
    }
  }
  __syncthreads();
  if (lh[t]) atomicAdd(&hist[t], lh[t]);
}

// ============================================================================
// K6: compact: keys > T -> sel (unordered; rank pass sorts later);
//     keys == T -> tie buffer.
// ============================================================================
__global__ __launch_bounds__(256) void k_compact(
    const U32* __restrict__ keys, U32* __restrict__ cnt,
    U64* __restrict__ sel, U32* __restrict__ tiebuf)
{
  int tid = blockIdx.x * 256 + threadIdx.x;
  if (tid >= NBOX) return;
  U32 k = keys[tid];
  U32 T = cnt[0];
  if (k > T) {
    U32 p = atomicAdd(&cnt[8], 1u);
    sel[p] = ((U64)k << 32) | (U64)(0xFFFFFFFFu - (U32)tid);
  } else if (k == T) {
    U32 p = atomicAdd(&cnt[9], 1u);
    if (p < 4096) tiebuf[p] = (U32)tid;
  }
}

// ============================================================================
// K7: resolve ==T ties by smallest index (stable top_k semantics)
// ============================================================================
__global__ __launch_bounds__(256) void k_ties(
    U32* __restrict__ cnt, const U32* __restrict__ tiebuf, U64* __restrict__ sel)
{
  __shared__ U32 tb[4096];
  int t = threadIdx.x;
  U32 m = cnt[9]; if (m > 4096u) m = 4096u;
  U32 need = cnt[1];
  U32 cgt  = cnt[2];
  U32 T    = cnt[0];
  for (U32 j = t; j < m; j += 256) tb[j] = tiebuf[j];
  __syncthreads();
  for (U32 x = t; x < m; x += 256) {
    U32 my = tb[x];
    U32 r = 0;
    for (U32 j = 0; j < m; ++j) r += (tb[j] < my) ? 1u : 0u;
    if (r < need) sel[cgt + r] = ((U64)T << 32) | (U64)(0xFFFFFFFFu - my);
  }
}

// ============================================================================
// K8: exact rank of each selected element (score desc, idx asc) -> sorted
// boxes + packed valid bits. 36M u64 compares, LDS-staged. Order-invariant
// wrt sel's (atomic-nondeterministic) storage order.
// ============================================================================
__global__ __launch_bounds__(256) void k_rank(
    const U64* __restrict__ sel, const float* __restrict__ boxes,
    float* __restrict__ sboxes, U64* __restrict__ validw)
{
  __shared__ U64 ss[PRE_N];
  int t = threadIdx.x;
  for (int j = t; j < PRE_N; j += 256) ss[j] = sel[j];
  __syncthreads();
  int i = blockIdx.x * 256 + t;
  if (i >= PRE_N) return;
  U64 C = ss[i];
  int r = 0;
  for (int j = 0; j < PRE_N; ++j) r += (ss[j] > C) ? 1 : 0;
  U32 key = (U32)(C >> 32);
  U32 idx = 0xFFFFFFFFu - (U32)(C & 0xFFFFFFFFull);
  *(float4*)&sboxes[(size_t)r*4] = *(const float4*)&boxes[(size_t)idx*4];
  if (key & 0x80000000u)
    atomicOr(&validw[r >> 6], 1ull << (r & 63));
}

// ============================================================================
// K9: IoU > 0.7 bitmask, COLUMN-word-major: maskT[cw*MROWS + i] bit x =
//     iou(row i, box cw*64+x) > thr. Upper triangle + diagonal only (NMS
//     reads only i >= cw*64). Rows 6000..6015 in touched blocks written as 0.
// ============================================================================
__global__ __launch_bounds__(256) void k_mask(
    const float* __restrict__ sboxes, U64* __restrict__ maskT)
{
  int cw = blockIdx.x, rg = blockIdx.y;
  if (rg < cw) return;                       // lower triangle unused by NMS
  int t = threadIdx.x;
  int lane = t & 63, wv = t >> 6;
  int col = cw * 64 + lane;
  int cc = (col < PRE_N) ? col : (PRE_N - 1);
  float4 cb = *(const float4*)&sboxes[(size_t)cc*4];
  float areaC = (cb.z - cb.x) * (cb.w - cb.y);
  bool colok = (col < PRE_N);
  for (int rr = wv; rr < 64; rr += 4) {
    int row = rg * 64 + rr;
    U64 word = 0;
    if (row < PRE_N) {
      float4 rb = *(const float4*)&sboxes[(size_t)row*4];
      float areaR = (rb.z - rb.x) * (rb.w - rb.y);
      float ix1 = fmaxf(rb.x, cb.x), iy1 = fmaxf(rb.y, cb.y);
      float ix2 = fminf(rb.z, cb.z), iy2 = fminf(rb.w, cb.w);
      float inter = fmaxf(ix2 - ix1, 0.f) * fmaxf(iy2 - iy1, 0.f);
      float uni = areaR + areaC - inter;
      float iou = inter / fmaxf(uni, 1e-9f);
      word = __ballot(colok && (iou > 0.7f));
    }
    if (lane == 0) maskT[(size_t)cw * MROWS + row] = word;
  }
}

// ============================================================================
// K10: sequential-equivalent NMS — SINGLE WAVE, chunked incremental
// suppression, LDS-staged via async global_load_lds (ZERO staged VGPRs).
// R4-R8 lesson: any register-staged pipeline here gets sunk (C loads) or
// spilled (asm loads) by the allocator. global_load_lds has no destination
// registers — nothing to sink/spill. Per chunk: issue all <=47 async 16B/lane
// slices, decide overlaps flight, one s_waitcnt vmcnt(0)+sched_barrier(0)
// (rule #18), consume from LDS. Clamped tail rows read zeros (k_mask writes
// rows 6000..6015 as 0) -> benign, deterministic.
// ============================================================================
__global__ __launch_bounds__(64, 1) void k_nms(
    const U64* __restrict__ maskT, const U64* __restrict__ validw,
    U64* __restrict__ keepw)
{
  __shared__ U32 sup[MROWS];
  __shared__ U64 vws[NWORD];
  __shared__ U64 stage[NSLOTMAX * 128];      // 47 slots x 128 U64 = 47KB
  int j = threadIdx.x;                       // 0..63
  for (int i = j; i < MROWS; i += 64) sup[i] = 0;
  if (j < NWORD) vws[j] = validw[j];
  if (j + 64 < NWORD) vws[j + 64] = validw[j + 64];
  U64 low = (j == 0) ? 0ull : (~0ull >> (64 - j));
  U64 intra = maskT[j];                      // chunk 0 diagonal word
  __syncthreads();
  for (int c = 0; c < NWORD; ++c) {
    const U64* colp = maskT + (size_t)c * MROWS;
    int base = (c + 1) * 64;
    int nslots = (PRE_N - base + 127) >> 7;  // 128 rows per slot; >=0 always
    // ---- issue async global->LDS stages (no VGPR data, cannot be defeated)
    for (int q = 0; q < nslots; ++q) {
      int r = base + (q << 7) + (j << 1);
      if (r > MROWS - 2) r = MROWS - 2;      // per-lane source clamp (reads 0s)
      __builtin_amdgcn_global_load_lds(
          (const __attribute__((address_space(1))) void*)(colp + r),
          (__attribute__((address_space(3))) void*)(&stage[q << 7]),
          16, 0, 0);
    }
    // ---- decide (overlaps DMA flight) ----
    U64 vw = vws[c];
    bool alive = (((vw >> j) & 1ull) != 0ull) && (sup[c * 64 + j] == 0u);
    U64 aliveW = __ballot(alive);
    bool myconf = alive && ((intra & aliveW & low) != 0ull);
    U64 confW = __ballot(myconf);
    U64 keep = aliveW & ~confW;              // non-conflicted alive are kept
    U64 rem = confW;                         // resolve conflicted ascending
    while (rem) {
      int b = __ffsll((unsigned long long)rem) - 1;
      rem &= rem - 1;
      U64 Z = __ballot((intra & keep & low) == 0ull);
      if ((Z >> b) & 1ull) keep |= (1ull << b);
    }
    if (j == 0) keepw[c] = keep;
    if (c + 1 < NWORD)                       // prefetch next diagonal word
      intra = maskT[(size_t)(c + 1) * MROWS + (c + 1) * 64 + j];
    // ---- single drain, then consume from LDS ----
    asm volatile("s_waitcnt vmcnt(0)" ::: "memory");
    __builtin_amdgcn_sched_barrier(0);
    if (keep) {                              // wave-uniform
      for (int q = 0; q < nslots; ++q) {
        int r = base + (q << 7) + (j << 1);
        if (r > MROWS - 2) r = MROWS - 2;
        U64 lo = stage[(q << 7) + (j << 1)];
        U64 hi = stage[(q << 7) + (j << 1) + 1];
        if (lo & keep) sup[r] = 1u;          // rows >= PRE_N: harmless, never read
        if (hi & keep) sup[r + 1] = 1u;
      }
    }
    __syncthreads();                         // orders sup[]/stage before next c
  }
}

// ============================================================================
// K11: proposals: prefix-popcount ranks, first 300 kept boxes, zeros elsewhere
// ============================================================================
__global__ __launch_bounds__(256) void k_out(
    const U64* __restrict__ keepw, const float* __restrict__ sboxes,
    float* __restrict__ prop)
{
  __shared__ U64 kw[NWORD];
  __shared__ U32 pre[NWORD + 1];
  int t = threadIdx.x;
  if (t < NWORD) kw[t] = keepw[t];
  __syncthreads();
  if (t == 0) {
    U32 s = 0;
    for (int w = 0; w < NWORD; ++w) { pre[w] = s; s += (U32)__popcll(kw[w]); }
    pre[NWORD] = s;
  }
  for (int x = t; x < POST_N * 4; x += 256) prop[x] = 0.f;
  __syncthreads();
  for (int i = t; i < PRE_N; i += 256) {
    int w = i >> 6, b = i & 63;
    if ((kw[w] >> b) & 1ull) {
      U64 lowb = (b == 0) ? 0ull : (~0ull >> (64 - b));
      U32 r = pre[w] + (U32)__popcll(kw[w] & lowb);
      if (r < POST_N)
        *(float4*)&prop[(size_t)r*4] = *(const float4*)&sboxes[(size_t)i*4];
    }
  }
}

// ============================================================================
extern "C" void kernel_launch(void* const* d_in, const int* in_sizes, int n_in,
                              void* d_out, int out_size, void* d_ws, size_t ws_size,
                              hipStream_t stream)
{
  (void)in_sizes; (void)n_in; (void)out_size;
  if (ws_size < WS_NEED) return;   // scratch too small; bail safely

  const float* feats = (const float*)d_in[0];
  const float* ancs  = (const float*)d_in[1];
  const float* W_b   = (const float*)d_in[3];
  const float* b_b   = (const float*)d_in[4];
  const float* W_cls = (const float*)d_in[5];
  const float* b_cls = (const float*)d_in[6];
  const float* W_reg = (const float*)d_in[7];
  const float* b_reg = (const float*)d_in[8];

  float* out    = (float*)d_out;
  float* outCls = out;                 // 90000
  float* outReg = out + 90000;         // 360000
  float* prop   = out + 450000;        // 1200

  char* ws = (char*)d_ws;
  float* H      = (float*)(ws + OFF_H);
  float* boxes  = (float*)(ws + OFF_BOXES);
  U32*   keys   = (U32*)  (ws + OFF_KEYS);
  U64*   maskT  = (U64*)  (ws + OFF_MASKT);
  U64*   sel    = (U64*)  (ws + OFF_SEL);
  float* sboxes = (float*)(ws + OFF_SBOX);
  U64*   validw = (U64*)  (ws + OFF_VALIDW);
  U64*   keepw  = (U64*)  (ws + OFF_KEEPW);
  U32*   hist   = (U32*)  (ws + OFF_HIST);
  U32*   cnt    = (U32*)  (ws + OFF_CNT);
  U32*   tiebuf = (U32*)  (ws + OFF_TIE);

  k_gemm1<<<dim3(8, 79), dim3(256), 0, stream>>>(feats, W_b, b_b, H,
                                                 hist, cnt, (U32*)validw);
  k_heads<<<dim3(2500), dim3(256), 0, stream>>>(H, W_cls, b_cls, W_reg, b_reg,
                                                outCls, outReg);
  k_decode<<<dim3(352), dim3(256), 0, stream>>>(outCls, outReg, ancs,
                                                boxes, keys, hist);
  k_scan<<<dim3(1), dim3(256), 0, stream>>>(hist, cnt, 0);
  for (int lv = 1; lv <= 3; ++lv) {
    k_hist<<<dim3(352), dim3(256), 0, stream>>>(keys, hist, cnt, lv);
    k_scan<<<dim3(1), dim3(256), 0, stream>>>(hist, cnt, lv);
  }
  k_compact<<<dim3(352), dim3(256), 0, stream>>>(keys, cnt, sel, tiebuf);
  k_ties<<<dim3(1), dim3(256), 0, stream>>>(cnt, tiebuf, sel);
  k_rank<<<dim3(24), dim3(256), 0, stream>>>(sel, boxes, sboxes, validw);
  k_mask<<<dim3(94, 94), dim3(256), 0, stream>>>(sboxes, maskT);
  k_nms<<<dim3(1), dim3(64), 0, stream>>>(maskT, validw, keepw);
  k_out<<<dim3(1), dim3(256), 0, stream>>>(keepw, sboxes, prop);
}

// Round 10
// 672.188 us; speedup vs baseline: 1.6947x; 1.0309x over previous
//
#include <hip/hip_runtime.h>
#include <math.h>

typedef unsigned int U32;
typedef unsigned long long U64;

#define NBOX   90000
#define NPIX   10000
#define KDIM   1024
#define CBOT   512
#define PRE_N  6000
#define POST_N 300
#define NWORD  94      // ceil(6000/64)
#define MROWS  6016    // 94*64 rows allocated per column in maskT

// ---------------- workspace layout (byte offsets, all 16B aligned) ----------
#define OFF_H       0ULL          // 10000*512*4   = 20480000
#define OFF_BOXES   20480000ULL   // 90000*4*4     = 1440000
#define OFF_KEYS    21920000ULL   // 90000*4       = 360000
#define OFF_MASKT   22280000ULL   // 94*6016*8     = 4524032 (column-major)
#define OFF_SEL     26804032ULL   // 6000*8        = 48000
#define OFF_SBOX    26852032ULL   // 6000*4*4      = 96000
#define OFF_VALIDW  26948032ULL   // 94*8 -> 768
#define OFF_KEEPW   26948800ULL   // 768
#define OFF_HIST    26949568ULL   // 256*4 -> 1024
#define OFF_CNT     26950592ULL   // 64*4  -> 256
#define OFF_TIE     26950848ULL   // 4096*4 = 16384
#define WS_NEED     26967232ULL

// cnt[] slots: 0=prefix/T  1=target_remaining(->need_ties)  2=c_gt  8=n_gt atomic  9=n_tie atomic

// ============================================================================
// K1: h = relu(feats @ W_b + b_b)   fp32, 128x128 tile, 8x8 acc/thread, BK=16.
// Per-output FMA chain is ascending-k => bitwise identical to the previous
// 128x64 version (top-k ordering safe). 4 b128 LDS reads per 64 FMAs.
// Also zero-inits hist/cnt/validw (block (0,0) only).
// ============================================================================
__global__ __launch_bounds__(256) void k_gemm1(
    const float* __restrict__ A, const float* __restrict__ W,
    const float* __restrict__ bias, float* __restrict__ H,
    U32* __restrict__ hist, U32* __restrict__ cnt, U32* __restrict__ validw32)
{
  int t = threadIdx.x;
  if (blockIdx.x == 0 && blockIdx.y == 0) {
    hist[t] = 0;
    if (t < 64)  cnt[t] = (t == 1) ? (U32)PRE_N : 0u;
    if (t < 188) validw32[t] = 0;
  }
  __shared__ float As[16][132];   // [k][m], pad keeps rows 16B aligned
  __shared__ float Bs[16][132];   // [k][n]
  int m0 = blockIdx.y * 128, n0 = blockIdx.x * 128;
  int tm = t >> 4, tn = t & 15;
  int ar = t >> 1, ac = (t & 1) << 3;   // A stage: row ar, cols ac..ac+7
  int bk = t >> 4, bc = (t & 15) << 3;  // B stage: row bk, cols bc..bc+7
  float acc[8][8];
#pragma unroll
  for (int i = 0; i < 8; ++i)
#pragma unroll
    for (int j = 0; j < 8; ++j) acc[i][j] = 0.f;

  for (int k0 = 0; k0 < KDIM; k0 += 16) {
    int r = m0 + ar;
    float4 a0 = make_float4(0.f,0.f,0.f,0.f), a1 = a0;
    if (r < NPIX) {
      a0 = *(const float4*)&A[(size_t)r * KDIM + k0 + ac];
      a1 = *(const float4*)&A[(size_t)r * KDIM + k0 + ac + 4];
    }
    float4 b0 = *(const float4*)&W[(size_t)(k0 + bk) * CBOT + n0 + bc];
    float4 b1 = *(const float4*)&W[(size_t)(k0 + bk) * CBOT + n0 + bc + 4];
    __syncthreads();
    As[ac+0][ar] = a0.x; As[ac+1][ar] = a0.y; As[ac+2][ar] = a0.z; As[ac+3][ar] = a0.w;
    As[ac+4][ar] = a1.x; As[ac+5][ar] = a1.y; As[ac+6][ar] = a1.z; As[ac+7][ar] = a1.w;
    *(float4*)&Bs[bk][bc] = b0;
    *(float4*)&Bs[bk][bc+4] = b1;
    __syncthreads();
#pragma unroll
    for (int kk = 0; kk < 16; ++kk) {
      float4 av0 = *(float4*)&As[kk][tm*8];
      float4 av1 = *(float4*)&As[kk][tm*8+4];
      float4 bv0 = *(float4*)&Bs[kk][tn*8];
      float4 bv1 = *(float4*)&Bs[kk][tn*8+4];
      float am[8] = {av0.x,av0.y,av0.z,av0.w,av1.x,av1.y,av1.z,av1.w};
      float bm[8] = {bv0.x,bv0.y,bv0.z,bv0.w,bv1.x,bv1.y,bv1.z,bv1.w};
#pragma unroll
      for (int i = 0; i < 8; ++i)
#pragma unroll
        for (int j = 0; j < 8; ++j)
          acc[i][j] = fmaf(am[i], bm[j], acc[i][j]);
    }
  }
  float4 bb0 = *(const float4*)&bias[n0 + tn*8];
  float4 bb1 = *(const float4*)&bias[n0 + tn*8 + 4];
  float bm[8] = {bb0.x,bb0.y,bb0.z,bb0.w,bb1.x,bb1.y,bb1.z,bb1.w};
#pragma unroll
  for (int i = 0; i < 8; ++i) {
    int r = m0 + tm*8 + i;
    if (r < NPIX) {
      float4 o0, o1;
      o0.x = fmaxf(acc[i][0] + bm[0], 0.f);
      o0.y = fmaxf(acc[i][1] + bm[1], 0.f);
      o0.z = fmaxf(acc[i][2] + bm[2], 0.f);
      o0.w = fmaxf(acc[i][3] + bm[3], 0.f);
      o1.x = fmaxf(acc[i][4] + bm[4], 0.f);
      o1.y = fmaxf(acc[i][5] + bm[5], 0.f);
      o1.z = fmaxf(acc[i][6] + bm[6], 0.f);
      o1.w = fmaxf(acc[i][7] + bm[7], 0.f);
      *(float4*)&H[(size_t)r * CBOT + n0 + tn*8]     = o0;
      *(float4*)&H[(size_t)r * CBOT + n0 + tn*8 + 4] = o1;
    }
  }
}

// ============================================================================
// K2: cls = sigmoid(h@W_cls+b_cls), reg = h@W_reg+b_reg  (4 pixels / block)
// ============================================================================
__global__ __launch_bounds__(256) void k_heads(
    const float* __restrict__ H, const float* __restrict__ Wc,
    const float* __restrict__ bc, const float* __restrict__ Wr,
    const float* __restrict__ br, float* __restrict__ outCls,
    float* __restrict__ outReg)
{
  __shared__ float hs[4][516];
  int t = threadIdx.x;
  int p0 = blockIdx.x * 4;
  for (int q = t; q < 512; q += 256) {
    int row = q >> 7, off = (q & 127) << 2;
    *(float4*)&hs[row][off] = *(const float4*)&H[(size_t)(p0 + row) * CBOT + off];
  }
  __syncthreads();
  if (t < 180) {
    int pl = t / 45, c = t % 45;
    const float* wp; int stride; float bval;
    if (c < 9) { wp = Wc + c;       stride = 9;  bval = bc[c]; }
    else       { wp = Wr + (c - 9); stride = 36; bval = br[c - 9]; }
    float s = 0.f;
    const float* hrow = hs[pl];
    for (int k = 0; k < CBOT; k += 4) {
      float4 hv = *(const float4*)&hrow[k];
      s = fmaf(hv.x, wp[(size_t)(k+0)*stride], s);
      s = fmaf(hv.y, wp[(size_t)(k+1)*stride], s);
      s = fmaf(hv.z, wp[(size_t)(k+2)*stride], s);
      s = fmaf(hv.w, wp[(size_t)(k+3)*stride], s);
    }
    s += bval;
    int p = p0 + pl;
    if (c < 9) outCls[(size_t)p*9 + c] = 1.f / (1.f + expf(-s));
    else       outReg[(size_t)p*36 + (c - 9)] = s;
  }
}

// ============================================================================
// K3: decode boxes, size filter, sortable keys, level-0 histogram
// ============================================================================
__global__ __launch_bounds__(256) void k_decode(
    const float* __restrict__ outCls, const float* __restrict__ outReg,
    const float* __restrict__ ancs, float* __restrict__ boxes,
    U32* __restrict__ keys, U32* __restrict__ hist)
{
  __shared__ U32 lh[256];
  int t = threadIdx.x;
  int tid = blockIdx.x * 256 + t;
  lh[t] = 0;
  __syncthreads();
  if (tid < NBOX) {
    float sc = outCls[tid];
    float4 of = *(const float4*)&outReg[(size_t)tid*4];
    float4 an = *(const float4*)&ancs[(size_t)tid*4];
    float cx = an.x + of.x * an.z;
    float cy = an.y + of.y * an.w;
    float ww = an.z * expf(of.z);
    float hh = an.w * expf(of.w);
    float x1 = fminf(fmaxf(cx - ww * 0.5f, 0.f), 1.f);
    float y1 = fminf(fmaxf(cy - hh * 0.5f, 0.f), 1.f);
    float x2 = fminf(fmaxf(cx + ww * 0.5f, 0.f), 1.f);
    float y2 = fminf(fmaxf(cy + hh * 0.5f, 0.f), 1.f);
    bool ok = ((x2 - x1) * 100.f >= 1.f) && ((y2 - y1) * 100.f >= 1.f);
    float msc = ok ? sc : -1.f;
    U32 u = __float_as_uint(msc);
    U32 key = (u & 0x80000000u) ? ~u : (u | 0x80000000u);
    keys[tid] = key;
    *(float4*)&boxes[(size_t)tid*4] = make_float4(x1, y1, x2, y2);
    atomicAdd(&lh[key >> 24], 1u);
  }
  __syncthreads();
  if (lh[t]) atomicAdd(&hist[t], lh[t]);
}

// ============================================================================
// K4: radix-select scan step (one per level). Picks digit, updates prefix /
// remaining target / count-above, zeroes hist for next level.
// ============================================================================
__global__ __launch_bounds__(256) void k_scan(
    U32* __restrict__ hist, U32* __restrict__ cnt, int level)
{
  __shared__ U32 lh[256];
  int t = threadIdx.x;
  lh[t] = hist[t];
  __syncthreads();
  if (t == 0) {
    U32 target = cnt[1];
    U32 cum = 0;
    int d = 255;
    while (d > 0) {
      U32 hh = lh[d];
      if (cum + hh >= target) break;
      cum += hh; --d;
    }
    cnt[0] |= ((U32)d) << (24 - 8*level);
    cnt[1] = target - cum;
    cnt[2] += cum;
  }
  __syncthreads();
  hist[t] = 0;
}

// ============================================================================
// K5: filtered histogram for levels 1..3
// ============================================================================
__global__ __launch_bounds__(256) void k_hist(
    const U32* __restrict__ keys, U32* __restrict__ hist,
    const U32* __restrict__ cnt, int level)
{
  __shared__ U32 lh[256];
  int t = threadIdx.x;
  int tid = blockIdx.x * 256 + t;
  lh[t] = 0;
  __syncthreads();
  if (tid < NBOX) {
    U32 k = keys[tid];
    U32 prefix = cnt[0];
    int shift = 32 - 8*level;
    if ((k >> shift) == (prefix >> shift)) {
      U32 bin = (k >> (24 - 8*level)) & 0xFFu;
      atomicAdd(&lh[bin], 1u);
    }
  }
  __syncthreads();
  if (lh[t]) atomicAdd(&hist[t], lh[t]);
}

// ============================================================================
// K6: compact: keys > T -> sel (unordered; rank pass sorts later);
//     keys == T -> tie buffer.
// ============================================================================
__global__ __launch_bounds__(256) void k_compact(
    const U32* __restrict__ keys, U32* __restrict__ cnt,
    U64* __restrict__ sel, U32* __restrict__ tiebuf)
{
  int tid = blockIdx.x * 256 + threadIdx.x;
  if (tid >= NBOX) return;
  U32 k = keys[tid];
  U32 T = cnt[0];
  if (k > T) {
    U32 p = atomicAdd(&cnt[8], 1u);
    sel[p] = ((U64)k << 32) | (U64)(0xFFFFFFFFu - (U32)tid);
  } else if (k == T) {
    U32 p = atomicAdd(&cnt[9], 1u);
    if (p < 4096) tiebuf[p] = (U32)tid;
  }
}

// ============================================================================
// K7: resolve ==T ties by smallest index (stable top_k semantics)
// ============================================================================
__global__ __launch_bounds__(256) void k_ties(
    U32* __restrict__ cnt, const U32* __restrict__ tiebuf, U64* __restrict__ sel)
{
  __shared__ U32 tb[4096];
  int t = threadIdx.x;
  U32 m = cnt[9]; if (m > 4096u) m = 4096u;
  U32 need = cnt[1];
  U32 cgt  = cnt[2];
  U32 T    = cnt[0];
  for (U32 j = t; j < m; j += 256) tb[j] = tiebuf[j];
  __syncthreads();
  for (U32 x = t; x < m; x += 256) {
    U32 my = tb[x];
    U32 r = 0;
    for (U32 j = 0; j < m; ++j) r += (tb[j] < my) ? 1u : 0u;
    if (r < need) sel[cgt + r] = ((U64)T << 32) | (U64)(0xFFFFFFFFu - my);
  }
}

// ============================================================================
// K8: exact rank of each selected element (score desc, idx asc) -> sorted
// boxes + packed valid bits. 36M u64 compares, LDS-staged. Order-invariant
// wrt sel's (atomic-nondeterministic) storage order.
// ============================================================================
__global__ __launch_bounds__(256) void k_rank(
    const U64* __restrict__ sel, const float* __restrict__ boxes,
    float* __restrict__ sboxes, U64* __restrict__ validw)
{
  __shared__ U64 ss[PRE_N];
  int t = threadIdx.x;
  for (int j = t; j < PRE_N; j += 256) ss[j] = sel[j];
  __syncthreads();
  int i = blockIdx.x * 256 + t;
  if (i >= PRE_N) return;
  U64 C = ss[i];
  int r = 0;
  for (int j = 0; j < PRE_N; ++j) r += (ss[j] > C) ? 1 : 0;
  U32 key = (U32)(C >> 32);
  U32 idx = 0xFFFFFFFFu - (U32)(C & 0xFFFFFFFFull);
  *(float4*)&sboxes[(size_t)r*4] = *(const float4*)&boxes[(size_t)idx*4];
  if (key & 0x80000000u)
    atomicOr(&validw[r >> 6], 1ull << (r & 63));
}

// ============================================================================
// K9: IoU > 0.7 bitmask, COLUMN-word-major: maskT[cw*MROWS + i] bit x =
//     iou(row i, box cw*64+x) > thr. Upper triangle + diagonal only (NMS
//     reads only i >= cw*64). Rows 6000..6015 in touched blocks written as 0.
// ============================================================================
__global__ __launch_bounds__(256) void k_mask(
    const float* __restrict__ sboxes, U64* __restrict__ maskT)
{
  int cw = blockIdx.x, rg = blockIdx.y;
  if (rg < cw) return;                       // lower triangle unused by NMS
  int t = threadIdx.x;
  int lane = t & 63, wv = t >> 6;
  int col = cw * 64 + lane;
  int cc = (col < PRE_N) ? col : (PRE_N - 1);
  float4 cb = *(const float4*)&sboxes[(size_t)cc*4];
  float areaC = (cb.z - cb.x) * (cb.w - cb.y);
  bool colok = (col < PRE_N);
  for (int rr = wv; rr < 64; rr += 4) {
    int row = rg * 64 + rr;
    U64 word = 0;
    if (row < PRE_N) {
      float4 rb = *(const float4*)&sboxes[(size_t)row*4];
      float areaR = (rb.z - rb.x) * (rb.w - rb.y);
      float ix1 = fmaxf(rb.x, cb.x), iy1 = fmaxf(rb.y, cb.y);
      float ix2 = fminf(rb.z, cb.z), iy2 = fminf(rb.w, cb.w);
      float inter = fmaxf(ix2 - ix1, 0.f) * fmaxf(iy2 - iy1, 0.f);
      float uni = areaR + areaC - inter;
      float iou = inter / fmaxf(uni, 1e-9f);
      word = __ballot(colok && (iou > 0.7f));
    }
    if (lane == 0) maskT[(size_t)cw * MROWS + row] = word;
  }
}

// ============================================================================
// K10: sequential-equivalent NMS — SINGLE WAVE (R6 config, best measured at
// ~210us across 6 variants; single-wave serial scan floor). Chunked
// incremental suppression; all column-c loads issued as plain C ulonglong2
// groups before decide. Register-staging beyond this gets sunk/spilled by the
// allocator (R4-R8); LDS-DMA staging measured slower (R9: 270us).
// ============================================================================
__global__ __launch_bounds__(64, 1) void k_nms(
    const U64* __restrict__ maskT, const U64* __restrict__ validw,
    U64* __restrict__ keepw)
{
  __shared__ U32 sup[MROWS];
  __shared__ U64 vws[NWORD];
  int j = threadIdx.x;                       // 0..63
  for (int i = j; i < MROWS; i += 64) sup[i] = 0;
  if (j < NWORD) vws[j] = validw[j];
  if (j + 64 < NWORD) vws[j + 64] = validw[j + 64];
  U64 low = (j == 0) ? 0ull : (~0ull >> (64 - j));
  U64 intra = maskT[j];                      // chunk 0 diagonal word
  __syncthreads();
  for (int c = 0; c < NWORD; ++c) {
    const U64* colp = maskT + (size_t)c * MROWS;
    int base = (c + 1) * 64;
    bool g0 = base          < PRE_N;         // wave-uniform group presence
    bool g1 = base + 2048   < PRE_N;
    bool g2 = base + 4096   < PRE_N;
    ulonglong2 m0[16], m1[16], m2[16];
    // ---- issue ALL column-c loads before decide (independent of keep) ----
    if (g0) {
#pragma unroll
      for (int q = 0; q < 16; ++q) {
        int r = base + (q << 7) + (j << 1);
        r = (r > MROWS - 2) ? MROWS - 2 : r;
        m0[q] = *(const ulonglong2*)(colp + r);
      }
    }
    if (g1) {
#pragma unroll
      for (int q = 0; q < 16; ++q) {
        int r = base + 2048 + (q << 7) + (j << 1);
        r = (r > MROWS - 2) ? MROWS - 2 : r;
        m1[q] = *(const ulonglong2*)(colp + r);
      }
    }
    if (g2) {
#pragma unroll
      for (int q = 0; q < 16; ++q) {
        int r = base + 4096 + (q << 7) + (j << 1);
        r = (r > MROWS - 2) ? MROWS - 2 : r;
        m2[q] = *(const ulonglong2*)(colp + r);
      }
    }
    // ---- decide (overlaps load latency) ----
    U64 vw = vws[c];
    bool alive = (((vw >> j) & 1ull) != 0ull) && (sup[c * 64 + j] == 0u);
    U64 aliveW = __ballot(alive);
    bool myconf = alive && ((intra & aliveW & low) != 0ull);
    U64 confW = __ballot(myconf);
    U64 keep = aliveW & ~confW;              // non-conflicted alive are kept
    U64 rem = confW;                         // resolve conflicted ascending
    while (rem) {
      int b = __ffsll((unsigned long long)rem) - 1;
      rem &= rem - 1;
      U64 Z = __ballot((intra & keep & low) == 0ull);
      if ((Z >> b) & 1ull) keep |= (1ull << b);
    }
    if (j == 0) keepw[c] = keep;
    if (c + 1 < NWORD)                       // prefetch next diagonal word
      intra = maskT[(size_t)(c + 1) * MROWS + (c + 1) * 64 + j];
    // ---- apply suppression ----
    if (keep) {                              // wave-uniform
      if (g0) {
#pragma unroll
        for (int q = 0; q < 16; ++q) {
          int r = base + (q << 7) + (j << 1);
          r = (r > MROWS - 2) ? MROWS - 2 : r;
          if (m0[q].x & keep) sup[r] = 1u;
          if (m0[q].y & keep) sup[r + 1] = 1u;
        }
      }
      if (g1) {
#pragma unroll
        for (int q = 0; q < 16; ++q) {
          int r = base + 2048 + (q << 7) + (j << 1);
          r = (r > MROWS - 2) ? MROWS - 2 : r;
          if (m1[q].x & keep) sup[r] = 1u;
          if (m1[q].y & keep) sup[r + 1] = 1u;
        }
      }
      if (g2) {
#pragma unroll
        for (int q = 0; q < 16; ++q) {
          int r = base + 4096 + (q << 7) + (j << 1);
          r = (r > MROWS - 2) ? MROWS - 2 : r;
          if (m2[q].x & keep) sup[r] = 1u;
          if (m2[q].y & keep) sup[r + 1] = 1u;
        }
      }
    }
    __syncthreads();                         // orders sup[] before next decide
  }
}

// ============================================================================
// K11: proposals: prefix-popcount ranks, first 300 kept boxes, zeros elsewhere
// ============================================================================
__global__ __launch_bounds__(256) void k_out(
    const U64* __restrict__ keepw, const float* __restrict__ sboxes,
    float* __restrict__ prop)
{
  __shared__ U64 kw[NWORD];
  __shared__ U32 pre[NWORD + 1];
  int t = threadIdx.x;
  if (t < NWORD) kw[t] = keepw[t];
  __syncthreads();
  if (t == 0) {
    U32 s = 0;
    for (int w = 0; w < NWORD; ++w) { pre[w] = s; s += (U32)__popcll(kw[w]); }
    pre[NWORD] = s;
  }
  for (int x = t; x < POST_N * 4; x += 256) prop[x] = 0.f;
  __syncthreads();
  for (int i = t; i < PRE_N; i += 256) {
    int w = i >> 6, b = i & 63;
    if ((kw[w] >> b) & 1ull) {
      U64 lowb = (b == 0) ? 0ull : (~0ull >> (64 - b));
      U32 r = pre[w] + (U32)__popcll(kw[w] & lowb);
      if (r < POST_N)
        *(float4*)&prop[(size_t)r*4] = *(const float4*)&sboxes[(size_t)i*4];
    }
  }
}

// ============================================================================
extern "C" void kernel_launch(void* const* d_in, const int* in_sizes, int n_in,
                              void* d_out, int out_size, void* d_ws, size_t ws_size,
                              hipStream_t stream)
{
  (void)in_sizes; (void)n_in; (void)out_size;
  if (ws_size < WS_NEED) return;   // scratch too small; bail safely

  const float* feats = (const float*)d_in[0];
  const float* ancs  = (const float*)d_in[1];
  const float* W_b   = (const float*)d_in[3];
  const float* b_b   = (const float*)d_in[4];
  const float* W_cls = (const float*)d_in[5];
  const float* b_cls = (const float*)d_in[6];
  const float* W_reg = (const float*)d_in[7];
  const float* b_reg = (const float*)d_in[8];

  float* out    = (float*)d_out;
  float* outCls = out;                 // 90000
  float* outReg = out + 90000;         // 360000
  float* prop   = out + 450000;        // 1200

  char* ws = (char*)d_ws;
  float* H      = (float*)(ws + OFF_H);
  float* boxes  = (float*)(ws + OFF_BOXES);
  U32*   keys   = (U32*)  (ws + OFF_KEYS);
  U64*   maskT  = (U64*)  (ws + OFF_MASKT);
  U64*   sel    = (U64*)  (ws + OFF_SEL);
  float* sboxes = (float*)(ws + OFF_SBOX);
  U64*   validw = (U64*)  (ws + OFF_VALIDW);
  U64*   keepw  = (U64*)  (ws + OFF_KEEPW);
  U32*   hist   = (U32*)  (ws + OFF_HIST);
  U32*   cnt    = (U32*)  (ws + OFF_CNT);
  U32*   tiebuf = (U32*)  (ws + OFF_TIE);

  k_gemm1<<<dim3(4, 79), dim3(256), 0, stream>>>(feats, W_b, b_b, H,
                                                 hist, cnt, (U32*)validw);
  k_heads<<<dim3(2500), dim3(256), 0, stream>>>(H, W_cls, b_cls, W_reg, b_reg,
                                                outCls, outReg);
  k_decode<<<dim3(352), dim3(256), 0, stream>>>(outCls, outReg, ancs,
                                                boxes, keys, hist);
  k_scan<<<dim3(1), dim3(256), 0, stream>>>(hist, cnt, 0);
  for (int lv = 1; lv <= 3; ++lv) {
    k_hist<<<dim3(352), dim3(256), 0, stream>>>(keys, hist, cnt, lv);
    k_scan<<<dim3(1), dim3(256), 0, stream>>>(hist, cnt, lv);
  }
  k_compact<<<dim3(352), dim3(256), 0, stream>>>(keys, cnt, sel, tiebuf);
  k_ties<<<dim3(1), dim3(256), 0, stream>>>(cnt, tiebuf, sel);
  k_rank<<<dim3(24), dim3(256), 0, stream>>>(sel, boxes, sboxes, validw);
  k_mask<<<dim3(94, 94), dim3(256), 0, stream>>>(sboxes, maskT);
  k_nms<<<dim3(1), dim3(64), 0, stream>>>(maskT, validw, keepw);
  k_out<<<dim3(1), dim3(256), 0, stream>>>(keepw, sboxes, prop);
}

// Round 11
// 663.482 us; speedup vs baseline: 1.7170x; 1.0131x over previous
//
#include <hip/hip_runtime.h>
#include <math.h>

typedef unsigned int U32;
typedef unsigned long long U64;

#define NBOX   90000
#define NPIX   10000
#define KDIM   1024
#define CBOT   512
#define PRE_N  6000
#define POST_N 300
#define NWORD  94      // ceil(6000/64)
#define MROWS  6016    // 94*64 rows allocated per column in maskT

// ---------------- workspace layout (byte offsets, all 16B aligned) ----------
#define OFF_H       0ULL          // 10000*512*4   = 20480000
#define OFF_BOXES   20480000ULL   // 90000*4*4     = 1440000
#define OFF_KEYS    21920000ULL   // 90000*4       = 360000
#define OFF_MASKT   22280000ULL   // 94*6016*8     = 4524032 (column-major)
#define OFF_SEL     26804032ULL   // 6000*8        = 48000
#define OFF_SBOX    26852032ULL   // 6000*4*4      = 96000
#define OFF_VALIDW  26948032ULL   // 94*8 -> 768
#define OFF_KEEPW   26948800ULL   // 768
#define OFF_HIST    26949568ULL   // 256*4 -> 1024
#define OFF_CNT     26950592ULL   // 64*4  -> 256
#define OFF_TIE     26950848ULL   // 4096*4 = 16384
#define WS_NEED     26967232ULL

// cnt[] slots: 0=prefix/T  1=target_remaining(->need_ties)  2=c_gt  8=n_gt atomic  9=n_tie atomic

// ============================================================================
// K1: h = relu(feats @ W_b + b_b)  fp32, 128x128 tile, 8x(4+4) acc/thread.
// R10 counters: VGPR=52 (acc forced out of VGPRs by occupancy heuristic),
// 1.29e7 LDS bank conflicts (B-read stride 8 floats = 4-way). Fixes:
// (1) __launch_bounds__(256,1): 512-VGPR budget, acc stays in VGPRs.
// (2) B fragment = two b128 at tn*4 and 64+tn*4: stride 4 floats = 2-way
//     aliasing (free). Column remap only; per-(row,col) k-order unchanged
//     => H bitwise identical.
// (3) next-tile global loads issued after stage-barrier, BEFORE FMA loop:
//     HBM latency hides under 2048 cyc of FMAs.
// Also zero-inits hist/cnt/validw (block (0,0) only).
// ============================================================================
__global__ __launch_bounds__(256, 1) void k_gemm1(
    const float* __restrict__ A, const float* __restrict__ W,
    const float* __restrict__ bias, float* __restrict__ H,
    U32* __restrict__ hist, U32* __restrict__ cnt, U32* __restrict__ validw32)
{
  int t = threadIdx.x;
  if (blockIdx.x == 0 && blockIdx.y == 0) {
    hist[t] = 0;
    if (t < 64)  cnt[t] = (t == 1) ? (U32)PRE_N : 0u;
    if (t < 188) validw32[t] = 0;
  }
  __shared__ float As[16][132];   // [k][m], pad keeps rows 16B aligned
  __shared__ float Bs[16][132];   // [k][n]
  int m0 = blockIdx.y * 128, n0 = blockIdx.x * 128;
  int tm = t >> 4, tn = t & 15;
  int ar = t >> 1, ac = (t & 1) << 3;   // A stage: row ar, cols ac..ac+7
  int bk = t >> 4, bc = (t & 15) << 3;  // B stage: row bk, cols bc..bc+7
  float acc[8][8];
#pragma unroll
  for (int i = 0; i < 8; ++i)
#pragma unroll
    for (int j = 0; j < 8; ++j) acc[i][j] = 0.f;

  // prologue: first tile's loads
  int arow = m0 + ar;
  float4 a0 = make_float4(0.f,0.f,0.f,0.f), a1 = a0;
  if (arow < NPIX) {
    a0 = *(const float4*)&A[(size_t)arow * KDIM + ac];
    a1 = *(const float4*)&A[(size_t)arow * KDIM + ac + 4];
  }
  float4 b0 = *(const float4*)&W[(size_t)bk * CBOT + n0 + bc];
  float4 b1 = *(const float4*)&W[(size_t)bk * CBOT + n0 + bc + 4];

  for (int k0 = 0; k0 < KDIM; k0 += 16) {
    __syncthreads();                 // prior FMA readers done
    As[ac+0][ar] = a0.x; As[ac+1][ar] = a0.y; As[ac+2][ar] = a0.z; As[ac+3][ar] = a0.w;
    As[ac+4][ar] = a1.x; As[ac+5][ar] = a1.y; As[ac+6][ar] = a1.z; As[ac+7][ar] = a1.w;
    *(float4*)&Bs[bk][bc]   = b0;
    *(float4*)&Bs[bk][bc+4] = b1;
    __syncthreads();
    if (k0 + 16 < KDIM) {            // issue next-tile loads BEFORE FMA loop
      int kn = k0 + 16;
      if (arow < NPIX) {
        a0 = *(const float4*)&A[(size_t)arow * KDIM + kn + ac];
        a1 = *(const float4*)&A[(size_t)arow * KDIM + kn + ac + 4];
      }
      b0 = *(const float4*)&W[(size_t)(kn + bk) * CBOT + n0 + bc];
      b1 = *(const float4*)&W[(size_t)(kn + bk) * CBOT + n0 + bc + 4];
    }
#pragma unroll
    for (int kk = 0; kk < 16; ++kk) {
      float4 av0 = *(float4*)&As[kk][tm*8];
      float4 av1 = *(float4*)&As[kk][tm*8+4];
      float4 bv0 = *(float4*)&Bs[kk][tn*4];        // 2-way aliasing: free
      float4 bv1 = *(float4*)&Bs[kk][64 + tn*4];
      float am[8] = {av0.x,av0.y,av0.z,av0.w,av1.x,av1.y,av1.z,av1.w};
      float bm[8] = {bv0.x,bv0.y,bv0.z,bv0.w,bv1.x,bv1.y,bv1.z,bv1.w};
#pragma unroll
      for (int i = 0; i < 8; ++i)
#pragma unroll
        for (int j = 0; j < 8; ++j)
          acc[i][j] = fmaf(am[i], bm[j], acc[i][j]);
    }
  }
  float4 bb0 = *(const float4*)&bias[n0 + tn*4];
  float4 bb1 = *(const float4*)&bias[n0 + 64 + tn*4];
  float bm[8] = {bb0.x,bb0.y,bb0.z,bb0.w,bb1.x,bb1.y,bb1.z,bb1.w};
#pragma unroll
  for (int i = 0; i < 8; ++i) {
    int r = m0 + tm*8 + i;
    if (r < NPIX) {
      float4 o0, o1;
      o0.x = fmaxf(acc[i][0] + bm[0], 0.f);
      o0.y = fmaxf(acc[i][1] + bm[1], 0.f);
      o0.z = fmaxf(acc[i][2] + bm[2], 0.f);
      o0.w = fmaxf(acc[i][3] + bm[3], 0.f);
      o1.x = fmaxf(acc[i][4] + bm[4], 0.f);
      o1.y = fmaxf(acc[i][5] + bm[5], 0.f);
      o1.z = fmaxf(acc[i][6] + bm[6], 0.f);
      o1.w = fmaxf(acc[i][7] + bm[7], 0.f);
      *(float4*)&H[(size_t)r * CBOT + n0 + tn*4]      = o0;
      *(float4*)&H[(size_t)r * CBOT + n0 + 64 + tn*4] = o1;
    }
  }
}

// ============================================================================
// K2: cls = sigmoid(h@W_cls+b_cls), reg = h@W_reg+b_reg  (4 pixels / block)
// ============================================================================
__global__ __launch_bounds__(256) void k_heads(
    const float* __restrict__ H, const float* __restrict__ Wc,
    const float* __restrict__ bc, const float* __restrict__ Wr,
    const float* __restrict__ br, float* __restrict__ outCls,
    float* __restrict__ outReg)
{
  __shared__ float hs[4][516];
  int t = threadIdx.x;
  int p0 = blockIdx.x * 4;
  for (int q = t; q < 512; q += 256) {
    int row = q >> 7, off = (q & 127) << 2;
    *(float4*)&hs[row][off] = *(const float4*)&H[(size_t)(p0 + row) * CBOT + off];
  }
  __syncthreads();
  if (t < 180) {
    int pl = t / 45, c = t % 45;
    const float* wp; int stride; float bval;
    if (c < 9) { wp = Wc + c;       stride = 9;  bval = bc[c]; }
    else       { wp = Wr + (c - 9); stride = 36; bval = br[c - 9]; }
    float s = 0.f;
    const float* hrow = hs[pl];
    for (int k = 0; k < CBOT; k += 4) {
      float4 hv = *(const float4*)&hrow[k];
      s = fmaf(hv.x, wp[(size_t)(k+0)*stride], s);
      s = fmaf(hv.y, wp[(size_t)(k+1)*stride], s);
      s = fmaf(hv.z, wp[(size_t)(k+2)*stride], s);
      s = fmaf(hv.w, wp[(size_t)(k+3)*stride], s);
    }
    s += bval;
    int p = p0 + pl;
    if (c < 9) outCls[(size_t)p*9 + c] = 1.f / (1.f + expf(-s));
    else       outReg[(size_t)p*36 + (c - 9)] = s;
  }
}

// ============================================================================
// K3: decode boxes, size filter, sortable keys, level-0 histogram
// ============================================================================
__global__ __launch_bounds__(256) void k_decode(
    const float* __restrict__ outCls, const float* __restrict__ outReg,
    const float* __restrict__ ancs, float* __restrict__ boxes,
    U32* __restrict__ keys, U32* __restrict__ hist)
{
  __shared__ U32 lh[256];
  int t = threadIdx.x;
  int tid = blockIdx.x * 256 + t;
  lh[t] = 0;
  __syncthreads();
  if (tid < NBOX) {
    float sc = outCls[tid];
    float4 of = *(const float4*)&outReg[(size_t)tid*4];
    float4 an = *(const float4*)&ancs[(size_t)tid*4];
    float cx = an.x + of.x * an.z;
    float cy = an.y + of.y * an.w;
    float ww = an.z * expf(of.z);
    float hh = an.w * expf(of.w);
    float x1 = fminf(fmaxf(cx - ww * 0.5f, 0.f), 1.f);
    float y1 = fminf(fmaxf(cy - hh * 0.5f, 0.f), 1.f);
    float x2 = fminf(fmaxf(cx + ww * 0.5f, 0.f), 1.f);
    float y2 = fminf(fmaxf(cy + hh * 0.5f, 0.f), 1.f);
    bool ok = ((x2 - x1) * 100.f >= 1.f) && ((y2 - y1) * 100.f >= 1.f);
    float msc = ok ? sc : -1.f;
    U32 u = __float_as_uint(msc);
    U32 key = (u & 0x80000000u) ? ~u : (u | 0x80000000u);
    keys[tid] = key;
    *(float4*)&boxes[(size_t)tid*4] = make_float4(x1, y1, x2, y2);
    atomicAdd(&lh[key >> 24], 1u);
  }
  __syncthreads();
  if (lh[t]) atomicAdd(&hist[t], lh[t]);
}

// ============================================================================
// K4: radix-select scan step (one per level). Picks digit, updates prefix /
// remaining target / count-above, zeroes hist for next level.
// ============================================================================
__global__ __launch_bounds__(256) void k_scan(
    U32* __restrict__ hist, U32* __restrict__ cnt, int level)
{
  __shared__ U32 lh[256];
  int t = threadIdx.x;
  lh[t] = hist[t];
  __syncthreads();
  if (t == 0) {
    U32 target = cnt[1];
    U32 cum = 0;
    int d = 255;
    while (d > 0) {
      U32 hh = lh[d];
      if (cum + hh >= target) break;
      cum += hh; --d;
    }
    cnt[0] |= ((U32)d) << (24 - 8*level);
    cnt[1] = target - cum;
    cnt[2] += cum;
  }
  __syncthreads();
  hist[t] = 0;
}

// ============================================================================
// K5: filtered histogram for levels 1..3
// ============================================================================
__global__ __launch_bounds__(256) void k_hist(
    const U32* __restrict__ keys, U32* __restrict__ hist,
    const U32* __restrict__ cnt, int level)
{
  __shared__ U32 lh[256];
  int t = threadIdx.x;
  int tid = blockIdx.x * 256 + t;
  lh[t] = 0;
  __syncthreads();
  if (tid < NBOX) {
    U32 k = keys[tid];
    U32 prefix = cnt[0];
    int shift = 32 - 8*level;
    if ((k >> shift) == (prefix >> shift)) {
      U32 bin = (k >> (24 - 8*level)) & 0xFFu;
      atomicAdd(&lh[bin], 1u);
    }
  }
  __syncthreads();
  if (lh[t]) atomicAdd(&hist[t], lh[t]);
}

// ============================================================================
// K6: compact: keys > T -> sel (unordered; rank pass sorts later);
//     keys == T -> tie buffer.
// ============================================================================
__global__ __launch_bounds__(256) void k_compact(
    const U32* __restrict__ keys, U32* __restrict__ cnt,
    U64* __restrict__ sel, U32* __restrict__ tiebuf)
{
  int tid = blockIdx.x * 256 + threadIdx.x;
  if (tid >= NBOX) return;
  U32 k = keys[tid];
  U32 T = cnt[0];
  if (k > T) {
    U32 p = atomicAdd(&cnt[8], 1u);
    sel[p] = ((U64)k << 32) | (U64)(0xFFFFFFFFu - (U32)tid);
  } else if (k == T) {
    U32 p = atomicAdd(&cnt[9], 1u);
    if (p < 4096) tiebuf[p] = (U32)tid;
  }
}

// ============================================================================
// K7: resolve ==T ties by smallest index (stable top_k semantics)
// ============================================================================
__global__ __launch_bounds__(256) void k_ties(
    U32* __restrict__ cnt, const U32* __restrict__ tiebuf, U64* __restrict__ sel)
{
  __shared__ U32 tb[4096];
  int t = threadIdx.x;
  U32 m = cnt[9]; if (m > 4096u) m = 4096u;
  U32 need = cnt[1];
  U32 cgt  = cnt[2];
  U32 T    = cnt[0];
  for (U32 j = t; j < m; j += 256) tb[j] = tiebuf[j];
  __syncthreads();
  for (U32 x = t; x < m; x += 256) {
    U32 my = tb[x];
    U32 r = 0;
    for (U32 j = 0; j < m; ++j) r += (tb[j] < my) ? 1u : 0u;
    if (r < need) sel[cgt + r] = ((U64)T << 32) | (U64)(0xFFFFFFFFu - my);
  }
}

// ============================================================================
// K8: exact rank of each selected element (score desc, idx asc) -> sorted
// boxes + packed valid bits. 36M u64 compares, LDS-staged. Order-invariant
// wrt sel's (atomic-nondeterministic) storage order.
// ============================================================================
__global__ __launch_bounds__(256) void k_rank(
    const U64* __restrict__ sel, const float* __restrict__ boxes,
    float* __restrict__ sboxes, U64* __restrict__ validw)
{
  __shared__ U64 ss[PRE_N];
  int t = threadIdx.x;
  for (int j = t; j < PRE_N; j += 256) ss[j] = sel[j];
  __syncthreads();
  int i = blockIdx.x * 256 + t;
  if (i >= PRE_N) return;
  U64 C = ss[i];
  int r = 0;
  for (int j = 0; j < PRE_N; ++j) r += (ss[j] > C) ? 1 : 0;
  U32 key = (U32)(C >> 32);
  U32 idx = 0xFFFFFFFFu - (U32)(C & 0xFFFFFFFFull);
  *(float4*)&sboxes[(size_t)r*4] = *(const float4*)&boxes[(size_t)idx*4];
  if (key & 0x80000000u)
    atomicOr(&validw[r >> 6], 1ull << (r & 63));
}

// ============================================================================
// K9: IoU > 0.7 bitmask, COLUMN-word-major: maskT[cw*MROWS + i] bit x =
//     iou(row i, box cw*64+x) > thr. Upper triangle + diagonal only (NMS
//     reads only i >= cw*64). Rows 6000..6015 in touched blocks written as 0.
// ============================================================================
__global__ __launch_bounds__(256) void k_mask(
    const float* __restrict__ sboxes, U64* __restrict__ maskT)
{
  int cw = blockIdx.x, rg = blockIdx.y;
  if (rg < cw) return;                       // lower triangle unused by NMS
  int t = threadIdx.x;
  int lane = t & 63, wv = t >> 6;
  int col = cw * 64 + lane;
  int cc = (col < PRE_N) ? col : (PRE_N - 1);
  float4 cb = *(const float4*)&sboxes[(size_t)cc*4];
  float areaC = (cb.z - cb.x) * (cb.w - cb.y);
  bool colok = (col < PRE_N);
  for (int rr = wv; rr < 64; rr += 4) {
    int row = rg * 64 + rr;
    U64 word = 0;
    if (row < PRE_N) {
      float4 rb = *(const float4*)&sboxes[(size_t)row*4];
      float areaR = (rb.z - rb.x) * (rb.w - rb.y);
      float ix1 = fmaxf(rb.x, cb.x), iy1 = fmaxf(rb.y, cb.y);
      float ix2 = fminf(rb.z, cb.z), iy2 = fminf(rb.w, cb.w);
      float inter = fmaxf(ix2 - ix1, 0.f) * fmaxf(iy2 - iy1, 0.f);
      float uni = areaR + areaC - inter;
      float iou = inter / fmaxf(uni, 1e-9f);
      word = __ballot(colok && (iou > 0.7f));
    }
    if (lane == 0) maskT[(size_t)cw * MROWS + row] = word;
  }
}

// ============================================================================
// K10: sequential-equivalent NMS — SINGLE WAVE (R6 config, best measured at
// ~210us across 6 variants; single-wave serial scan floor). Chunked
// incremental suppression; all column-c loads issued as plain C ulonglong2
// groups before decide. Register-staging beyond this gets sunk/spilled by the
// allocator (R4-R8); LDS-DMA staging measured slower (R9: 270us).
// ============================================================================
__global__ __launch_bounds__(64, 1) void k_nms(
    const U64* __restrict__ maskT, const U64* __restrict__ validw,
    U64* __restrict__ keepw)
{
  __shared__ U32 sup[MROWS];
  __shared__ U64 vws[NWORD];
  int j = threadIdx.x;                       // 0..63
  for (int i = j; i < MROWS; i += 64) sup[i] = 0;
  if (j < NWORD) vws[j] = validw[j];
  if (j + 64 < NWORD) vws[j + 64] = validw[j + 64];
  U64 low = (j == 0) ? 0ull : (~0ull >> (64 - j));
  U64 intra = maskT[j];                      // chunk 0 diagonal word
  __syncthreads();
  for (int c = 0; c < NWORD; ++c) {
    const U64* colp = maskT + (size_t)c * MROWS;
    int base = (c + 1) * 64;
    bool g0 = base          < PRE_N;         // wave-uniform group presence
    bool g1 = base + 2048   < PRE_N;
    bool g2 = base + 4096   < PRE_N;
    ulonglong2 m0[16], m1[16], m2[16];
    // ---- issue ALL column-c loads before decide (independent of keep) ----
    if (g0) {
#pragma unroll
      for (int q = 0; q < 16; ++q) {
        int r = base + (q << 7) + (j << 1);
        r = (r > MROWS - 2) ? MROWS - 2 : r;
        m0[q] = *(const ulonglong2*)(colp + r);
      }
    }
    if (g1) {
#pragma unroll
      for (int q = 0; q < 16; ++q) {
        int r = base + 2048 + (q << 7) + (j << 1);
        r = (r > MROWS - 2) ? MROWS - 2 : r;
        m1[q] = *(const ulonglong2*)(colp + r);
      }
    }
    if (g2) {
#pragma unroll
      for (int q = 0; q < 16; ++q) {
        int r = base + 4096 + (q << 7) + (j << 1);
        r = (r > MROWS - 2) ? MROWS - 2 : r;
        m2[q] = *(const ulonglong2*)(colp + r);
      }
    }
    // ---- decide (overlaps load latency) ----
    U64 vw = vws[c];
    bool alive = (((vw >> j) & 1ull) != 0ull) && (sup[c * 64 + j] == 0u);
    U64 aliveW = __ballot(alive);
    bool myconf = alive && ((intra & aliveW & low) != 0ull);
    U64 confW = __ballot(myconf);
    U64 keep = aliveW & ~confW;              // non-conflicted alive are kept
    U64 rem = confW;                         // resolve conflicted ascending
    while (rem) {
      int b = __ffsll((unsigned long long)rem) - 1;
      rem &= rem - 1;
      U64 Z = __ballot((intra & keep & low) == 0ull);
      if ((Z >> b) & 1ull) keep |= (1ull << b);
    }
    if (j == 0) keepw[c] = keep;
    if (c + 1 < NWORD)                       // prefetch next diagonal word
      intra = maskT[(size_t)(c + 1) * MROWS + (c + 1) * 64 + j];
    // ---- apply suppression ----
    if (keep) {                              // wave-uniform
      if (g0) {
#pragma unroll
        for (int q = 0; q < 16; ++q) {
          int r = base + (q << 7) + (j << 1);
          r = (r > MROWS - 2) ? MROWS - 2 : r;
          if (m0[q].x & keep) sup[r] = 1u;
          if (m0[q].y & keep) sup[r + 1] = 1u;
        }
      }
      if (g1) {
#pragma unroll
        for (int q = 0; q < 16; ++q) {
          int r = base + 2048 + (q << 7) + (j << 1);
          r = (r > MROWS - 2) ? MROWS - 2 : r;
          if (m1[q].x & keep) sup[r] = 1u;
          if (m1[q].y & keep) sup[r + 1] = 1u;
        }
      }
      if (g2) {
#pragma unroll
        for (int q = 0; q < 16; ++q) {
          int r = base + 4096 + (q << 7) + (j << 1);
          r = (r > MROWS - 2) ? MROWS - 2 : r;
          if (m2[q].x & keep) sup[r] = 1u;
          if (m2[q].y & keep) sup[r + 1] = 1u;
        }
      }
    }
    __syncthreads();                         // orders sup[] before next decide
  }
}

// ============================================================================
// K11: proposals: prefix-popcount ranks, first 300 kept boxes, zeros elsewhere
// ============================================================================
__global__ __launch_bounds__(256) void k_out(
    const U64* __restrict__ keepw, const float* __restrict__ sboxes,
    float* __restrict__ prop)
{
  __shared__ U64 kw[NWORD];
  __shared__ U32 pre[NWORD + 1];
  int t = threadIdx.x;
  if (t < NWORD) kw[t] = keepw[t];
  __syncthreads();
  if (t == 0) {
    U32 s = 0;
    for (int w = 0; w < NWORD; ++w) { pre[w] = s; s += (U32)__popcll(kw[w]); }
    pre[NWORD] = s;
  }
  for (int x = t; x < POST_N * 4; x += 256) prop[x] = 0.f;
  __syncthreads();
  for (int i = t; i < PRE_N; i += 256) {
    int w = i >> 6, b = i & 63;
    if ((kw[w] >> b) & 1ull) {
      U64 lowb = (b == 0) ? 0ull : (~0ull >> (64 - b));
      U32 r = pre[w] + (U32)__popcll(kw[w] & lowb);
      if (r < POST_N)
        *(float4*)&prop[(size_t)r*4] = *(const float4*)&sboxes[(size_t)i*4];
    }
  }
}

// ============================================================================
extern "C" void kernel_launch(void* const* d_in, const int* in_sizes, int n_in,
                              void* d_out, int out_size, void* d_ws, size_t ws_size,
                              hipStream_t stream)
{
  (void)in_sizes; (void)n_in; (void)out_size;
  if (ws_size < WS_NEED) return;   // scratch too small; bail safely

  const float* feats = (const float*)d_in[0];
  const float* ancs  = (const float*)d_in[1];
  const float* W_b   = (const float*)d_in[3];
  const float* b_b   = (const float*)d_in[4];
  const float* W_cls = (const float*)d_in[5];
  const float* b_cls = (const float*)d_in[6];
  const float* W_reg = (const float*)d_in[7];
  const float* b_reg = (const float*)d_in[8];

  float* out    = (float*)d_out;
  float* outCls = out;                 // 90000
  float* outReg = out + 90000;         // 360000
  float* prop   = out + 450000;        // 1200

  char* ws = (char*)d_ws;
  float* H      = (float*)(ws + OFF_H);
  float* boxes  = (float*)(ws + OFF_BOXES);
  U32*   keys   = (U32*)  (ws + OFF_KEYS);
  U64*   maskT  = (U64*)  (ws + OFF_MASKT);
  U64*   sel    = (U64*)  (ws + OFF_SEL);
  float* sboxes = (float*)(ws + OFF_SBOX);
  U64*   validw = (U64*)  (ws + OFF_VALIDW);
  U64*   keepw  = (U64*)  (ws + OFF_KEEPW);
  U32*   hist   = (U32*)  (ws + OFF_HIST);
  U32*   cnt    = (U32*)  (ws + OFF_CNT);
  U32*   tiebuf = (U32*)  (ws + OFF_TIE);

  k_gemm1<<<dim3(4, 79), dim3(256), 0, stream>>>(feats, W_b, b_b, H,
                                                 hist, cnt, (U32*)validw);
  k_heads<<<dim3(2500), dim3(256), 0, stream>>>(H, W_cls, b_cls, W_reg, b_reg,
                                                outCls, outReg);
  k_decode<<<dim3(352), dim3(256), 0, stream>>>(outCls, outReg, ancs,
                                                boxes, keys, hist);
  k_scan<<<dim3(1), dim3(256), 0, stream>>>(hist, cnt, 0);
  for (int lv = 1; lv <= 3; ++lv) {
    k_hist<<<dim3(352), dim3(256), 0, stream>>>(keys, hist, cnt, lv);
    k_scan<<<dim3(1), dim3(256), 0, stream>>>(hist, cnt, lv);
  }
  k_compact<<<dim3(352), dim3(256), 0, stream>>>(keys, cnt, sel, tiebuf);
  k_ties<<<dim3(1), dim3(256), 0, stream>>>(cnt, tiebuf, sel);
  k_rank<<<dim3(24), dim3(256), 0, stream>>>(sel, boxes, sboxes, validw);
  k_mask<<<dim3(94, 94), dim3(256), 0, stream>>>(sboxes, maskT);
  k_nms<<<dim3(1), dim3(64), 0, stream>>>(maskT, validw, keepw);
  k_out<<<dim3(1), dim3(256), 0, stream>>>(keepw, sboxes, prop);
}

// Round 12
// 623.846 us; speedup vs baseline: 1.8261x; 1.0635x over previous
//
#include <hip/hip_runtime.h>
#include <math.h>

typedef unsigned int U32;
typedef unsigned long long U64;

#define NBOX   90000
#define NPIX   10000
#define KDIM   1024
#define CBOT   512
#define PRE_N  6000
#define POST_N 300
#define NWORD  94      // ceil(6000/64)
#define MROWS  6016    // 94*64 rows allocated per column in maskT

// ---------------- workspace layout (byte offsets, all 16B aligned) ----------
#define OFF_H       0ULL          // 10000*512*4   = 20480000
#define OFF_BOXES   20480000ULL   // 90000*4*4     = 1440000
#define OFF_KEYS    21920000ULL   // 90000*4       = 360000
#define OFF_MASKT   22280000ULL   // 94*6016*8     = 4524032 (column-major)
#define OFF_SEL     26804032ULL   // 6000*8        = 48000
#define OFF_SBOX    26852032ULL   // 6000*4*4      = 96000
#define OFF_VALIDW  26948032ULL   // 94*8 -> 768
#define OFF_KEEPW   26948800ULL   // 768
#define OFF_HIST    26949568ULL   // 256*4 -> 1024
#define OFF_CNT     26950592ULL   // 64*4  -> 256
#define OFF_TIE     26950848ULL   // 4096*4 = 16384
#define WS_NEED     26967232ULL

// cnt[] slots: 0=prefix/T  1=target_remaining(->need_ties)  2=c_gt  8=n_gt atomic  9=n_tie atomic

// ============================================================================
// K1: h = relu(feats @ W_b + b_b)  fp32, 128x64 tile, 8x4 acc/thread, BK=16.
// R11 lesson: 128x128 grid=316 -> 1 wave/SIMD (Occupancy 10.5%), zero TLP,
// latency exposed (VALUBusy 45%). This round: 632 blocks, launch_bounds
// (256,4) -> ~4 blocks/CU co-resident, all blocks simultaneously resident;
// TLP hides LDS/staging latency. Bank-conflict-free staging/reads kept
// (2-way only = free). Per-output k-order ascending -> H bitwise identical.
// Also zero-inits hist/cnt/validw (block (0,0) only).
// ============================================================================
__global__ __launch_bounds__(256, 4) void k_gemm1(
    const float* __restrict__ A, const float* __restrict__ W,
    const float* __restrict__ bias, float* __restrict__ H,
    U32* __restrict__ hist, U32* __restrict__ cnt, U32* __restrict__ validw32)
{
  int t = threadIdx.x;
  if (blockIdx.x == 0 && blockIdx.y == 0) {
    hist[t] = 0;
    if (t < 64)  cnt[t] = (t == 1) ? (U32)PRE_N : 0u;
    if (t < 188) validw32[t] = 0;
  }
  __shared__ float As[16][132];   // [k][m], pad: bank stride 4 per k-row
  __shared__ float Bs[16][68];    // [k][n], 64 cols + pad
  int m0 = blockIdx.y * 128, n0 = blockIdx.x * 64;
  int tm = t >> 4, tn = t & 15;
  int ar = t >> 1, ac = (t & 1) << 3;   // A stage: row ar, cols ac..ac+7
  int bk = t >> 4, bc = (t & 15) << 2;  // B stage: row bk, cols bc..bc+3
  float acc[8][4];
#pragma unroll
  for (int i = 0; i < 8; ++i)
#pragma unroll
    for (int j = 0; j < 4; ++j) acc[i][j] = 0.f;

  // prologue: first tile's loads
  int arow = m0 + ar;
  float4 a0 = make_float4(0.f,0.f,0.f,0.f), a1 = a0;
  if (arow < NPIX) {
    a0 = *(const float4*)&A[(size_t)arow * KDIM + ac];
    a1 = *(const float4*)&A[(size_t)arow * KDIM + ac + 4];
  }
  float4 b0 = *(const float4*)&W[(size_t)bk * CBOT + n0 + bc];

  for (int k0 = 0; k0 < KDIM; k0 += 16) {
    __syncthreads();                 // prior FMA readers done
    As[ac+0][ar] = a0.x; As[ac+1][ar] = a0.y; As[ac+2][ar] = a0.z; As[ac+3][ar] = a0.w;
    As[ac+4][ar] = a1.x; As[ac+5][ar] = a1.y; As[ac+6][ar] = a1.z; As[ac+7][ar] = a1.w;
    *(float4*)&Bs[bk][bc] = b0;
    __syncthreads();
    if (k0 + 16 < KDIM) {            // issue next-tile loads BEFORE FMA loop
      int kn = k0 + 16;
      if (arow < NPIX) {
        a0 = *(const float4*)&A[(size_t)arow * KDIM + kn + ac];
        a1 = *(const float4*)&A[(size_t)arow * KDIM + kn + ac + 4];
      }
      b0 = *(const float4*)&W[(size_t)(kn + bk) * CBOT + n0 + bc];
    }
#pragma unroll
    for (int kk = 0; kk < 16; ++kk) {
      float4 av0 = *(float4*)&As[kk][tm*8];      // 16-lane broadcast, no conflict
      float4 av1 = *(float4*)&As[kk][tm*8+4];
      float4 bv0 = *(float4*)&Bs[kk][tn*4];      // 2-way aliasing: free
      float am[8] = {av0.x,av0.y,av0.z,av0.w,av1.x,av1.y,av1.z,av1.w};
      float bm[4] = {bv0.x,bv0.y,bv0.z,bv0.w};
#pragma unroll
      for (int i = 0; i < 8; ++i)
#pragma unroll
        for (int j = 0; j < 4; ++j)
          acc[i][j] = fmaf(am[i], bm[j], acc[i][j]);
    }
  }
  float4 bb = *(const float4*)&bias[n0 + tn*4];
  float bm[4] = {bb.x, bb.y, bb.z, bb.w};
#pragma unroll
  for (int i = 0; i < 8; ++i) {
    int r = m0 + tm*8 + i;
    if (r < NPIX) {
      float4 o;
      o.x = fmaxf(acc[i][0] + bm[0], 0.f);
      o.y = fmaxf(acc[i][1] + bm[1], 0.f);
      o.z = fmaxf(acc[i][2] + bm[2], 0.f);
      o.w = fmaxf(acc[i][3] + bm[3], 0.f);
      *(float4*)&H[(size_t)r * CBOT + n0 + tn*4] = o;
    }
  }
}

// ============================================================================
// K2: cls = sigmoid(h@W_cls+b_cls), reg = h@W_reg+b_reg  (4 pixels / block)
// ============================================================================
__global__ __launch_bounds__(256) void k_heads(
    const float* __restrict__ H, const float* __restrict__ Wc,
    const float* __restrict__ bc, const float* __restrict__ Wr,
    const float* __restrict__ br, float* __restrict__ outCls,
    float* __restrict__ outReg)
{
  __shared__ float hs[4][516];
  int t = threadIdx.x;
  int p0 = blockIdx.x * 4;
  for (int q = t; q < 512; q += 256) {
    int row = q >> 7, off = (q & 127) << 2;
    *(float4*)&hs[row][off] = *(const float4*)&H[(size_t)(p0 + row) * CBOT + off];
  }
  __syncthreads();
  if (t < 180) {
    int pl = t / 45, c = t % 45;
    const float* wp; int stride; float bval;
    if (c < 9) { wp = Wc + c;       stride = 9;  bval = bc[c]; }
    else       { wp = Wr + (c - 9); stride = 36; bval = br[c - 9]; }
    float s = 0.f;
    const float* hrow = hs[pl];
    for (int k = 0; k < CBOT; k += 4) {
      float4 hv = *(const float4*)&hrow[k];
      s = fmaf(hv.x, wp[(size_t)(k+0)*stride], s);
      s = fmaf(hv.y, wp[(size_t)(k+1)*stride], s);
      s = fmaf(hv.z, wp[(size_t)(k+2)*stride], s);
      s = fmaf(hv.w, wp[(size_t)(k+3)*stride], s);
    }
    s += bval;
    int p = p0 + pl;
    if (c < 9) outCls[(size_t)p*9 + c] = 1.f / (1.f + expf(-s));
    else       outReg[(size_t)p*36 + (c - 9)] = s;
  }
}

// ============================================================================
// K3: decode boxes, size filter, sortable keys, level-0 histogram
// ============================================================================
__global__ __launch_bounds__(256) void k_decode(
    const float* __restrict__ outCls, const float* __restrict__ outReg,
    const float* __restrict__ ancs, float* __restrict__ boxes,
    U32* __restrict__ keys, U32* __restrict__ hist)
{
  __shared__ U32 lh[256];
  int t = threadIdx.x;
  int tid = blockIdx.x * 256 + t;
  lh[t] = 0;
  __syncthreads();
  if (tid < NBOX) {
    float sc = outCls[tid];
    float4 of = *(const float4*)&outReg[(size_t)tid*4];
    float4 an = *(const float4*)&ancs[(size_t)tid*4];
    float cx = an.x + of.x * an.z;
    float cy = an.y + of.y * an.w;
    float ww = an.z * expf(of.z);
    float hh = an.w * expf(of.w);
    float x1 = fminf(fmaxf(cx - ww * 0.5f, 0.f), 1.f);
    float y1 = fminf(fmaxf(cy - hh * 0.5f, 0.f), 1.f);
    float x2 = fminf(fmaxf(cx + ww * 0.5f, 0.f), 1.f);
    float y2 = fminf(fmaxf(cy + hh * 0.5f, 0.f), 1.f);
    bool ok = ((x2 - x1) * 100.f >= 1.f) && ((y2 - y1) * 100.f >= 1.f);
    float msc = ok ? sc : -1.f;
    U32 u = __float_as_uint(msc);
    U32 key = (u & 0x80000000u) ? ~u : (u | 0x80000000u);
    keys[tid] = key;
    *(float4*)&boxes[(size_t)tid*4] = make_float4(x1, y1, x2, y2);
    atomicAdd(&lh[key >> 24], 1u);
  }
  __syncthreads();
  if (lh[t]) atomicAdd(&hist[t], lh[t]);
}

// ============================================================================
// K4: radix-select scan step (one per level). Picks digit, updates prefix /
// remaining target / count-above, zeroes hist for next level.
// ============================================================================
__global__ __launch_bounds__(256) void k_scan(
    U32* __restrict__ hist, U32* __restrict__ cnt, int level)
{
  __shared__ U32 lh[256];
  int t = threadIdx.x;
  lh[t] = hist[t];
  __syncthreads();
  if (t == 0) {
    U32 target = cnt[1];
    U32 cum = 0;
    int d = 255;
    while (d > 0) {
      U32 hh = lh[d];
      if (cum + hh >= target) break;
      cum += hh; --d;
    }
    cnt[0] |= ((U32)d) << (24 - 8*level);
    cnt[1] = target - cum;
    cnt[2] += cum;
  }
  __syncthreads();
  hist[t] = 0;
}

// ============================================================================
// K5: filtered histogram for levels 1..3
// ============================================================================
__global__ __launch_bounds__(256) void k_hist(
    const U32* __restrict__ keys, U32* __restrict__ hist,
    const U32* __restrict__ cnt, int level)
{
  __shared__ U32 lh[256];
  int t = threadIdx.x;
  int tid = blockIdx.x * 256 + t;
  lh[t] = 0;
  __syncthreads();
  if (tid < NBOX) {
    U32 k = keys[tid];
    U32 prefix = cnt[0];
    int shift = 32 - 8*level;
    if ((k >> shift) == (prefix >> shift)) {
      U32 bin = (k >> (24 - 8*level)) & 0xFFu;
      atomicAdd(&lh[bin], 1u);
    }
  }
  __syncthreads();
  if (lh[t]) atomicAdd(&hist[t], lh[t]);
}

// ============================================================================
// K6: compact: keys > T -> sel (unordered; rank pass sorts later);
//     keys == T -> tie buffer.
// ============================================================================
__global__ __launch_bounds__(256) void k_compact(
    const U32* __restrict__ keys, U32* __restrict__ cnt,
    U64* __restrict__ sel, U32* __restrict__ tiebuf)
{
  int tid = blockIdx.x * 256 + threadIdx.x;
  if (tid >= NBOX) return;
  U32 k = keys[tid];
  U32 T = cnt[0];
  if (k > T) {
    U32 p = atomicAdd(&cnt[8], 1u);
    sel[p] = ((U64)k << 32) | (U64)(0xFFFFFFFFu - (U32)tid);
  } else if (k == T) {
    U32 p = atomicAdd(&cnt[9], 1u);
    if (p < 4096) tiebuf[p] = (U32)tid;
  }
}

// ============================================================================
// K7: resolve ==T ties by smallest index (stable top_k semantics)
// ============================================================================
__global__ __launch_bounds__(256) void k_ties(
    U32* __restrict__ cnt, const U32* __restrict__ tiebuf, U64* __restrict__ sel)
{
  __shared__ U32 tb[4096];
  int t = threadIdx.x;
  U32 m = cnt[9]; if (m > 4096u) m = 4096u;
  U32 need = cnt[1];
  U32 cgt  = cnt[2];
  U32 T    = cnt[0];
  for (U32 j = t; j < m; j += 256) tb[j] = tiebuf[j];
  __syncthreads();
  for (U32 x = t; x < m; x += 256) {
    U32 my = tb[x];
    U32 r = 0;
    for (U32 j = 0; j < m; ++j) r += (tb[j] < my) ? 1u : 0u;
    if (r < need) sel[cgt + r] = ((U64)T << 32) | (U64)(0xFFFFFFFFu - my);
  }
}

// ============================================================================
// K8: exact rank of each selected element (score desc, idx asc) -> sorted
// boxes + packed valid bits. 36M u64 compares, LDS-staged. Order-invariant
// wrt sel's (atomic-nondeterministic) storage order.
// ============================================================================
__global__ __launch_bounds__(256) void k_rank(
    const U64* __restrict__ sel, const float* __restrict__ boxes,
    float* __restrict__ sboxes, U64* __restrict__ validw)
{
  __shared__ U64 ss[PRE_N];
  int t = threadIdx.x;
  for (int j = t; j < PRE_N; j += 256) ss[j] = sel[j];
  __syncthreads();
  int i = blockIdx.x * 256 + t;
  if (i >= PRE_N) return;
  U64 C = ss[i];
  int r = 0;
  for (int j = 0; j < PRE_N; ++j) r += (ss[j] > C) ? 1 : 0;
  U32 key = (U32)(C >> 32);
  U32 idx = 0xFFFFFFFFu - (U32)(C & 0xFFFFFFFFull);
  *(float4*)&sboxes[(size_t)r*4] = *(const float4*)&boxes[(size_t)idx*4];
  if (key & 0x80000000u)
    atomicOr(&validw[r >> 6], 1ull << (r & 63));
}

// ============================================================================
// K9: IoU > 0.7 bitmask, COLUMN-word-major: maskT[cw*MROWS + i] bit x =
//     iou(row i, box cw*64+x) > thr. Upper triangle + diagonal only (NMS
//     reads only i >= cw*64). Rows 6000..6015 in touched blocks written as 0.
// ============================================================================
__global__ __launch_bounds__(256) void k_mask(
    const float* __restrict__ sboxes, U64* __restrict__ maskT)
{
  int cw = blockIdx.x, rg = blockIdx.y;
  if (rg < cw) return;                       // lower triangle unused by NMS
  int t = threadIdx.x;
  int lane = t & 63, wv = t >> 6;
  int col = cw * 64 + lane;
  int cc = (col < PRE_N) ? col : (PRE_N - 1);
  float4 cb = *(const float4*)&sboxes[(size_t)cc*4];
  float areaC = (cb.z - cb.x) * (cb.w - cb.y);
  bool colok = (col < PRE_N);
  for (int rr = wv; rr < 64; rr += 4) {
    int row = rg * 64 + rr;
    U64 word = 0;
    if (row < PRE_N) {
      float4 rb = *(const float4*)&sboxes[(size_t)row*4];
      float areaR = (rb.z - rb.x) * (rb.w - rb.y);
      float ix1 = fmaxf(rb.x, cb.x), iy1 = fmaxf(rb.y, cb.y);
      float ix2 = fminf(rb.z, cb.z), iy2 = fminf(rb.w, cb.w);
      float inter = fmaxf(ix2 - ix1, 0.f) * fmaxf(iy2 - iy1, 0.f);
      float uni = areaR + areaC - inter;
      float iou = inter / fmaxf(uni, 1e-9f);
      word = __ballot(colok && (iou > 0.7f));
    }
    if (lane == 0) maskT[(size_t)cw * MROWS + row] = word;
  }
}

// ============================================================================
// K10: sequential-equivalent NMS — SINGLE WAVE (R6 config, measured floor
// ~210-216us across 7 variants). Chunked incremental suppression; loads
// issued as plain C ulonglong2 groups before decide.
// ============================================================================
__global__ __launch_bounds__(64, 1) void k_nms(
    const U64* __restrict__ maskT, const U64* __restrict__ validw,
    U64* __restrict__ keepw)
{
  __shared__ U32 sup[MROWS];
  __shared__ U64 vws[NWORD];
  int j = threadIdx.x;                       // 0..63
  for (int i = j; i < MROWS; i += 64) sup[i] = 0;
  if (j < NWORD) vws[j] = validw[j];
  if (j + 64 < NWORD) vws[j + 64] = validw[j + 64];
  U64 low = (j == 0) ? 0ull : (~0ull >> (64 - j));
  U64 intra = maskT[j];                      // chunk 0 diagonal word
  __syncthreads();
  for (int c = 0; c < NWORD; ++c) {
    const U64* colp = maskT + (size_t)c * MROWS;
    int base = (c + 1) * 64;
    bool g0 = base          < PRE_N;         // wave-uniform group presence
    bool g1 = base + 2048   < PRE_N;
    bool g2 = base + 4096   < PRE_N;
    ulonglong2 m0[16], m1[16], m2[16];
    // ---- issue ALL column-c loads before decide (independent of keep) ----
    if (g0) {
#pragma unroll
      for (int q = 0; q < 16; ++q) {
        int r = base + (q << 7) + (j << 1);
        r = (r > MROWS - 2) ? MROWS - 2 : r;
        m0[q] = *(const ulonglong2*)(colp + r);
      }
    }
    if (g1) {
#pragma unroll
      for (int q = 0; q < 16; ++q) {
        int r = base + 2048 + (q << 7) + (j << 1);
        r = (r > MROWS - 2) ? MROWS - 2 : r;
        m1[q] = *(const ulonglong2*)(colp + r);
      }
    }
    if (g2) {
#pragma unroll
      for (int q = 0; q < 16; ++q) {
        int r = base + 4096 + (q << 7) + (j << 1);
        r = (r > MROWS - 2) ? MROWS - 2 : r;
        m2[q] = *(const ulonglong2*)(colp + r);
      }
    }
    // ---- decide (overlaps load latency) ----
    U64 vw = vws[c];
    bool alive = (((vw >> j) & 1ull) != 0ull) && (sup[c * 64 + j] == 0u);
    U64 aliveW = __ballot(alive);
    bool myconf = alive && ((intra & aliveW & low) != 0ull);
    U64 confW = __ballot(myconf);
    U64 keep = aliveW & ~confW;              // non-conflicted alive are kept
    U64 rem = confW;                         // resolve conflicted ascending
    while (rem) {
      int b = __ffsll((unsigned long long)rem) - 1;
      rem &= rem - 1;
      U64 Z = __ballot((intra & keep & low) == 0ull);
      if ((Z >> b) & 1ull) keep |= (1ull << b);
    }
    if (j == 0) keepw[c] = keep;
    if (c + 1 < NWORD)                       // prefetch next diagonal word
      intra = maskT[(size_t)(c + 1) * MROWS + (c + 1) * 64 + j];
    // ---- apply suppression ----
    if (keep) {                              // wave-uniform
      if (g0) {
#pragma unroll
      for (int q = 0; q < 16; ++q) {
          int r = base + (q << 7) + (j << 1);
          r = (r > MROWS - 2) ? MROWS - 2 : r;
          if (m0[q].x & keep) sup[r] = 1u;
          if (m0[q].y & keep) sup[r + 1] = 1u;
        }
      }
      if (g1) {
#pragma unroll
        for (int q = 0; q < 16; ++q) {
          int r = base + 2048 + (q << 7) + (j << 1);
          r = (r > MROWS - 2) ? MROWS - 2 : r;
          if (m1[q].x & keep) sup[r] = 1u;
          if (m1[q].y & keep) sup[r + 1] = 1u;
        }
      }
      if (g2) {
#pragma unroll
        for (int q = 0; q < 16; ++q) {
          int r = base + 4096 + (q << 7) + (j << 1);
          r = (r > MROWS - 2) ? MROWS - 2 : r;
          if (m2[q].x & keep) sup[r] = 1u;
          if (m2[q].y & keep) sup[r + 1] = 1u;
        }
      }
    }
    __syncthreads();                         // orders sup[] before next decide
  }
}

// ============================================================================
// K11: proposals: prefix-popcount ranks, first 300 kept boxes, zeros elsewhere
// ============================================================================
__global__ __launch_bounds__(256) void k_out(
    const U64* __restrict__ keepw, const float* __restrict__ sboxes,
    float* __restrict__ prop)
{
  __shared__ U64 kw[NWORD];
  __shared__ U32 pre[NWORD + 1];
  int t = threadIdx.x;
  if (t < NWORD) kw[t] = keepw[t];
  __syncthreads();
  if (t == 0) {
    U32 s = 0;
    for (int w = 0; w < NWORD; ++w) { pre[w] = s; s += (U32)__popcll(kw[w]); }
    pre[NWORD] = s;
  }
  for (int x = t; x < POST_N * 4; x += 256) prop[x] = 0.f;
  __syncthreads();
  for (int i = t; i < PRE_N; i += 256) {
    int w = i >> 6, b = i & 63;
    if ((kw[w] >> b) & 1ull) {
      U64 lowb = (b == 0) ? 0ull : (~0ull >> (64 - b));
      U32 r = pre[w] + (U32)__popcll(kw[w] & lowb);
      if (r < POST_N)
        *(float4*)&prop[(size_t)r*4] = *(const float4*)&sboxes[(size_t)i*4];
    }
  }
}

// ============================================================================
extern "C" void kernel_launch(void* const* d_in, const int* in_sizes, int n_in,
                              void* d_out, int out_size, void* d_ws, size_t ws_size,
                              hipStream_t stream)
{
  (void)in_sizes; (void)n_in; (void)out_size;
  if (ws_size < WS_NEED) return;   // scratch too small; bail safely

  const float* feats = (const float*)d_in[0];
  const float* ancs  = (const float*)d_in[1];
  const float* W_b   = (const float*)d_in[3];
  const float* b_b   = (const float*)d_in[4];
  const float* W_cls = (const float*)d_in[5];
  const float* b_cls = (const float*)d_in[6];
  const float* W_reg = (const float*)d_in[7];
  const float* b_reg = (const float*)d_in[8];

  float* out    = (float*)d_out;
  float* outCls = out;                 // 90000
  float* outReg = out + 90000;         // 360000
  float* prop   = out + 450000;        // 1200

  char* ws = (char*)d_ws;
  float* H      = (float*)(ws + OFF_H);
  float* boxes  = (float*)(ws + OFF_BOXES);
  U32*   keys   = (U32*)  (ws + OFF_KEYS);
  U64*   maskT  = (U64*)  (ws + OFF_MASKT);
  U64*   sel    = (U64*)  (ws + OFF_SEL);
  float* sboxes = (float*)(ws + OFF_SBOX);
  U64*   validw = (U64*)  (ws + OFF_VALIDW);
  U64*   keepw  = (U64*)  (ws + OFF_KEEPW);
  U32*   hist   = (U32*)  (ws + OFF_HIST);
  U32*   cnt    = (U32*)  (ws + OFF_CNT);
  U32*   tiebuf = (U32*)  (ws + OFF_TIE);

  k_gemm1<<<dim3(8, 79), dim3(256), 0, stream>>>(feats, W_b, b_b, H,
                                                 hist, cnt, (U32*)validw);
  k_heads<<<dim3(2500), dim3(256), 0, stream>>>(H, W_cls, b_cls, W_reg, b_reg,
                                                outCls, outReg);
  k_decode<<<dim3(352), dim3(256), 0, stream>>>(outCls, outReg, ancs,
                                                boxes, keys, hist);
  k_scan<<<dim3(1), dim3(256), 0, stream>>>(hist, cnt, 0);
  for (int lv = 1; lv <= 3; ++lv) {
    k_hist<<<dim3(352), dim3(256), 0, stream>>>(keys, hist, cnt, lv);
    k_scan<<<dim3(1), dim3(256), 0, stream>>>(hist, cnt, lv);
  }
  k_compact<<<dim3(352), dim3(256), 0, stream>>>(keys, cnt, sel, tiebuf);
  k_ties<<<dim3(1), dim3(256), 0, stream>>>(cnt, tiebuf, sel);
  k_rank<<<dim3(24), dim3(256), 0, stream>>>(sel, boxes, sboxes, validw);
  k_mask<<<dim3(94, 94), dim3(256), 0, stream>>>(sboxes, maskT);
  k_nms<<<dim3(1), dim3(64), 0, stream>>>(maskT, validw, keepw);
  k_out<<<dim3(1), dim3(256), 0, stream>>>(keepw, sboxes, prop);
}

// Round 13
// 545.327 us; speedup vs baseline: 2.0890x; 1.1440x over previous
//
#include <hip/hip_runtime.h>
#include <math.h>

typedef unsigned int U32;
typedef unsigned long long U64;

#define NBOX   90000
#define NPIX   10000
#define KDIM   1024
#define CBOT   512
#define PRE_N  6000
#define POST_N 300
#define NWORD  94      // ceil(6000/64)
#define MROWS  6016    // 94*64 rows allocated per column in maskT

// ---------------- workspace layout (byte offsets, all 16B aligned) ----------
#define OFF_H       0ULL          // 10000*512*4   = 20480000
#define OFF_BOXES   20480000ULL   // 90000*4*4     = 1440000
#define OFF_KEYS    21920000ULL   // 90000*4       = 360000
#define OFF_MASKT   22280000ULL   // 94*6016*8     = 4524032 (column-major)
#define OFF_SEL     26804032ULL   // 6000*8        = 48000
#define OFF_SBOX    26852032ULL   // 6000*4*4      = 96000
#define OFF_VALIDW  26948032ULL   // 94*8 -> 768
#define OFF_KEEPW   26948800ULL   // 768
#define OFF_HIST    26949568ULL   // 256*4 -> 1024
#define OFF_CNT     26950592ULL   // 64*4  -> 256
#define OFF_TIE     26950848ULL   // 4096*4 = 16384
#define WS_NEED     26967232ULL

// cnt[] slots: 0=prefix/T  1=target_remaining(->need_ties)  2=c_gt  8=n_gt atomic  9=n_tie atomic

// ============================================================================
// K1: h = relu(feats @ W_b + b_b)  fp32, 128x64 tile, 8x4 acc/thread, BK=16.
// (256,4): 632 blocks all co-resident, TLP hides staging latency (R12 WIN).
// Bank-conflict-free staging/reads (2-way only = free). Per-output k-order
// ascending -> H bitwise identical across tilings.
// Also zero-inits hist/cnt/validw (block (0,0) only).
// ============================================================================
__global__ __launch_bounds__(256, 4) void k_gemm1(
    const float* __restrict__ A, const float* __restrict__ W,
    const float* __restrict__ bias, float* __restrict__ H,
    U32* __restrict__ hist, U32* __restrict__ cnt, U32* __restrict__ validw32)
{
  int t = threadIdx.x;
  if (blockIdx.x == 0 && blockIdx.y == 0) {
    hist[t] = 0;
    if (t < 64)  cnt[t] = (t == 1) ? (U32)PRE_N : 0u;
    if (t < 188) validw32[t] = 0;
  }
  __shared__ float As[16][132];   // [k][m], pad: bank stride 4 per k-row
  __shared__ float Bs[16][68];    // [k][n], 64 cols + pad
  int m0 = blockIdx.y * 128, n0 = blockIdx.x * 64;
  int tm = t >> 4, tn = t & 15;
  int ar = t >> 1, ac = (t & 1) << 3;   // A stage: row ar, cols ac..ac+7
  int bk = t >> 4, bc = (t & 15) << 2;  // B stage: row bk, cols bc..bc+3
  float acc[8][4];
#pragma unroll
  for (int i = 0; i < 8; ++i)
#pragma unroll
    for (int j = 0; j < 4; ++j) acc[i][j] = 0.f;

  // prologue: first tile's loads
  int arow = m0 + ar;
  float4 a0 = make_float4(0.f,0.f,0.f,0.f), a1 = a0;
  if (arow < NPIX) {
    a0 = *(const float4*)&A[(size_t)arow * KDIM + ac];
    a1 = *(const float4*)&A[(size_t)arow * KDIM + ac + 4];
  }
  float4 b0 = *(const float4*)&W[(size_t)bk * CBOT + n0 + bc];

  for (int k0 = 0; k0 < KDIM; k0 += 16) {
    __syncthreads();                 // prior FMA readers done
    As[ac+0][ar] = a0.x; As[ac+1][ar] = a0.y; As[ac+2][ar] = a0.z; As[ac+3][ar] = a0.w;
    As[ac+4][ar] = a1.x; As[ac+5][ar] = a1.y; As[ac+6][ar] = a1.z; As[ac+7][ar] = a1.w;
    *(float4*)&Bs[bk][bc] = b0;
    __syncthreads();
    if (k0 + 16 < KDIM) {            // issue next-tile loads BEFORE FMA loop
      int kn = k0 + 16;
      if (arow < NPIX) {
        a0 = *(const float4*)&A[(size_t)arow * KDIM + kn + ac];
        a1 = *(const float4*)&A[(size_t)arow * KDIM + kn + ac + 4];
      }
      b0 = *(const float4*)&W[(size_t)(kn + bk) * CBOT + n0 + bc];
    }
#pragma unroll
    for (int kk = 0; kk < 16; ++kk) {
      float4 av0 = *(float4*)&As[kk][tm*8];      // 16-lane broadcast, no conflict
      float4 av1 = *(float4*)&As[kk][tm*8+4];
      float4 bv0 = *(float4*)&Bs[kk][tn*4];      // 2-way aliasing: free
      float am[8] = {av0.x,av0.y,av0.z,av0.w,av1.x,av1.y,av1.z,av1.w};
      float bm[4] = {bv0.x,bv0.y,bv0.z,bv0.w};
#pragma unroll
      for (int i = 0; i < 8; ++i)
#pragma unroll
        for (int j = 0; j < 4; ++j)
          acc[i][j] = fmaf(am[i], bm[j], acc[i][j]);
    }
  }
  float4 bb = *(const float4*)&bias[n0 + tn*4];
  float bm[4] = {bb.x, bb.y, bb.z, bb.w};
#pragma unroll
  for (int i = 0; i < 8; ++i) {
    int r = m0 + tm*8 + i;
    if (r < NPIX) {
      float4 o;
      o.x = fmaxf(acc[i][0] + bm[0], 0.f);
      o.y = fmaxf(acc[i][1] + bm[1], 0.f);
      o.z = fmaxf(acc[i][2] + bm[2], 0.f);
      o.w = fmaxf(acc[i][3] + bm[3], 0.f);
      *(float4*)&H[(size_t)r * CBOT + n0 + tn*4] = o;
    }
  }
}

// ============================================================================
// K2: cls = sigmoid(h@W_cls+b_cls), reg = h@W_reg+b_reg  (4 pixels / block)
// ============================================================================
__global__ __launch_bounds__(256) void k_heads(
    const float* __restrict__ H, const float* __restrict__ Wc,
    const float* __restrict__ bc, const float* __restrict__ Wr,
    const float* __restrict__ br, float* __restrict__ outCls,
    float* __restrict__ outReg)
{
  __shared__ float hs[4][516];
  int t = threadIdx.x;
  int p0 = blockIdx.x * 4;
  for (int q = t; q < 512; q += 256) {
    int row = q >> 7, off = (q & 127) << 2;
    *(float4*)&hs[row][off] = *(const float4*)&H[(size_t)(p0 + row) * CBOT + off];
  }
  __syncthreads();
  if (t < 180) {
    int pl = t / 45, c = t % 45;
    const float* wp; int stride; float bval;
    if (c < 9) { wp = Wc + c;       stride = 9;  bval = bc[c]; }
    else       { wp = Wr + (c - 9); stride = 36; bval = br[c - 9]; }
    float s = 0.f;
    const float* hrow = hs[pl];
    for (int k = 0; k < CBOT; k += 4) {
      float4 hv = *(const float4*)&hrow[k];
      s = fmaf(hv.x, wp[(size_t)(k+0)*stride], s);
      s = fmaf(hv.y, wp[(size_t)(k+1)*stride], s);
      s = fmaf(hv.z, wp[(size_t)(k+2)*stride], s);
      s = fmaf(hv.w, wp[(size_t)(k+3)*stride], s);
    }
    s += bval;
    int p = p0 + pl;
    if (c < 9) outCls[(size_t)p*9 + c] = 1.f / (1.f + expf(-s));
    else       outReg[(size_t)p*36 + (c - 9)] = s;
  }
}

// ============================================================================
// K3: decode boxes, size filter, sortable keys, level-0 histogram
// ============================================================================
__global__ __launch_bounds__(256) void k_decode(
    const float* __restrict__ outCls, const float* __restrict__ outReg,
    const float* __restrict__ ancs, float* __restrict__ boxes,
    U32* __restrict__ keys, U32* __restrict__ hist)
{
  __shared__ U32 lh[256];
  int t = threadIdx.x;
  int tid = blockIdx.x * 256 + t;
  lh[t] = 0;
  __syncthreads();
  if (tid < NBOX) {
    float sc = outCls[tid];
    float4 of = *(const float4*)&outReg[(size_t)tid*4];
    float4 an = *(const float4*)&ancs[(size_t)tid*4];
    float cx = an.x + of.x * an.z;
    float cy = an.y + of.y * an.w;
    float ww = an.z * expf(of.z);
    float hh = an.w * expf(of.w);
    float x1 = fminf(fmaxf(cx - ww * 0.5f, 0.f), 1.f);
    float y1 = fminf(fmaxf(cy - hh * 0.5f, 0.f), 1.f);
    float x2 = fminf(fmaxf(cx + ww * 0.5f, 0.f), 1.f);
    float y2 = fminf(fmaxf(cy + hh * 0.5f, 0.f), 1.f);
    bool ok = ((x2 - x1) * 100.f >= 1.f) && ((y2 - y1) * 100.f >= 1.f);
    float msc = ok ? sc : -1.f;
    U32 u = __float_as_uint(msc);
    U32 key = (u & 0x80000000u) ? ~u : (u | 0x80000000u);
    keys[tid] = key;
    *(float4*)&boxes[(size_t)tid*4] = make_float4(x1, y1, x2, y2);
    atomicAdd(&lh[key >> 24], 1u);
  }
  __syncthreads();
  if (lh[t]) atomicAdd(&hist[t], lh[t]);
}

// ============================================================================
// K4: radix-select scan step (one per level). Picks digit, updates prefix /
// remaining target / count-above, zeroes hist for next level.
// ============================================================================
__global__ __launch_bounds__(256) void k_scan(
    U32* __restrict__ hist, U32* __restrict__ cnt, int level)
{
  __shared__ U32 lh[256];
  int t = threadIdx.x;
  lh[t] = hist[t];
  __syncthreads();
  if (t == 0) {
    U32 target = cnt[1];
    U32 cum = 0;
    int d = 255;
    while (d > 0) {
      U32 hh = lh[d];
      if (cum + hh >= target) break;
      cum += hh; --d;
    }
    cnt[0] |= ((U32)d) << (24 - 8*level);
    cnt[1] = target - cum;
    cnt[2] += cum;
  }
  __syncthreads();
  hist[t] = 0;
}

// ============================================================================
// K5: filtered histogram for levels 1..3
// ============================================================================
__global__ __launch_bounds__(256) void k_hist(
    const U32* __restrict__ keys, U32* __restrict__ hist,
    const U32* __restrict__ cnt, int level)
{
  __shared__ U32 lh[256];
  int t = threadIdx.x;
  int tid = blockIdx.x * 256 + t;
  lh[t] = 0;
  __syncthreads();
  if (tid < NBOX) {
    U32 k = keys[tid];
    U32 prefix = cnt[0];
    int shift = 32 - 8*level;
    if ((k >> shift) == (prefix >> shift)) {
      U32 bin = (k >> (24 - 8*level)) & 0xFFu;
      atomicAdd(&lh[bin], 1u);
    }
  }
  __syncthreads();
  if (lh[t]) atomicAdd(&hist[t], lh[t]);
}

// ============================================================================
// K6: compact: keys > T -> sel (unordered; rank pass sorts later);
//     keys == T -> tie buffer.
// ============================================================================
__global__ __launch_bounds__(256) void k_compact(
    const U32* __restrict__ keys, U32* __restrict__ cnt,
    U64* __restrict__ sel, U32* __restrict__ tiebuf)
{
  int tid = blockIdx.x * 256 + threadIdx.x;
  if (tid >= NBOX) return;
  U32 k = keys[tid];
  U32 T = cnt[0];
  if (k > T) {
    U32 p = atomicAdd(&cnt[8], 1u);
    sel[p] = ((U64)k << 32) | (U64)(0xFFFFFFFFu - (U32)tid);
  } else if (k == T) {
    U32 p = atomicAdd(&cnt[9], 1u);
    if (p < 4096) tiebuf[p] = (U32)tid;
  }
}

// ============================================================================
// K7: resolve ==T ties by smallest index (stable top_k semantics)
// ============================================================================
__global__ __launch_bounds__(256) void k_ties(
    U32* __restrict__ cnt, const U32* __restrict__ tiebuf, U64* __restrict__ sel)
{
  __shared__ U32 tb[4096];
  int t = threadIdx.x;
  U32 m = cnt[9]; if (m > 4096u) m = 4096u;
  U32 need = cnt[1];
  U32 cgt  = cnt[2];
  U32 T    = cnt[0];
  for (U32 j = t; j < m; j += 256) tb[j] = tiebuf[j];
  __syncthreads();
  for (U32 x = t; x < m; x += 256) {
    U32 my = tb[x];
    U32 r = 0;
    for (U32 j = 0; j < m; ++j) r += (tb[j] < my) ? 1u : 0u;
    if (r < need) sel[cgt + r] = ((U64)T << 32) | (U64)(0xFFFFFFFFu - my);
  }
}

// ============================================================================
// K8: exact rank of each selected element (score desc, idx asc) -> sorted
// boxes + packed valid bits. 36M u64 compares, LDS-staged. Order-invariant
// wrt sel's (atomic-nondeterministic) storage order.
// ============================================================================
__global__ __launch_bounds__(256) void k_rank(
    const U64* __restrict__ sel, const float* __restrict__ boxes,
    float* __restrict__ sboxes, U64* __restrict__ validw)
{
  __shared__ U64 ss[PRE_N];
  int t = threadIdx.x;
  for (int j = t; j < PRE_N; j += 256) ss[j] = sel[j];
  __syncthreads();
  int i = blockIdx.x * 256 + t;
  if (i >= PRE_N) return;
  U64 C = ss[i];
  int r = 0;
  for (int j = 0; j < PRE_N; ++j) r += (ss[j] > C) ? 1 : 0;
  U32 key = (U32)(C >> 32);
  U32 idx = 0xFFFFFFFFu - (U32)(C & 0xFFFFFFFFull);
  *(float4*)&sboxes[(size_t)r*4] = *(const float4*)&boxes[(size_t)idx*4];
  if (key & 0x80000000u)
    atomicOr(&validw[r >> 6], 1ull << (r & 63));
}

// ============================================================================
// K9: IoU > 0.7 bitmask, COLUMN-word-major: maskT[cw*MROWS + i] bit x =
//     iou(row i, box cw*64+x) > thr. Upper triangle + diagonal only (NMS
//     reads only i >= cw*64). Rows 6000..6015 in touched blocks written as 0.
// ============================================================================
__global__ __launch_bounds__(256) void k_mask(
    const float* __restrict__ sboxes, U64* __restrict__ maskT)
{
  int cw = blockIdx.x, rg = blockIdx.y;
  if (rg < cw) return;                       // lower triangle unused by NMS
  int t = threadIdx.x;
  int lane = t & 63, wv = t >> 6;
  int col = cw * 64 + lane;
  int cc = (col < PRE_N) ? col : (PRE_N - 1);
  float4 cb = *(const float4*)&sboxes[(size_t)cc*4];
  float areaC = (cb.z - cb.x) * (cb.w - cb.y);
  bool colok = (col < PRE_N);
  for (int rr = wv; rr < 64; rr += 4) {
    int row = rg * 64 + rr;
    U64 word = 0;
    if (row < PRE_N) {
      float4 rb = *(const float4*)&sboxes[(size_t)row*4];
      float areaR = (rb.z - rb.x) * (rb.w - rb.y);
      float ix1 = fmaxf(rb.x, cb.x), iy1 = fmaxf(rb.y, cb.y);
      float ix2 = fminf(rb.z, cb.z), iy2 = fminf(rb.w, cb.w);
      float inter = fmaxf(ix2 - ix1, 0.f) * fmaxf(iy2 - iy1, 0.f);
      float uni = areaR + areaC - inter;
      float iou = inter / fmaxf(uni, 1e-9f);
      word = __ballot(colok && (iou > 0.7f));
    }
    if (lane == 0) maskT[(size_t)cw * MROWS + row] = word;
  }
}

// ============================================================================
// K10: sequential-equivalent NMS — 8 WAVES (512 threads), strict barrier
// phases. Wave 0 decides chunk c (identical ballot/conflict-resolve logic to
// the proven single-wave version, reading LDS sup[]); barrier; ALL 512 lanes
// apply chunk-c suppression (12 predicated unrolled independent loads/lane,
// disjoint idempotent sup stores, no atomics); barrier. Decisions happen
// only at barrier-ordered points => bitwise-deterministic, same visit order
// as reference lax.scan. Clamped tail reads (rows 6000..6015) are written 0
// by k_mask and additionally guarded by i<PRE_N.
// R12 profile: single-wave nms = 210us = 1/3 of total with 255 CUs idle;
// decide chain is the only serial part, suppression is parallel.
// ============================================================================
__global__ __launch_bounds__(512, 1) void k_nms(
    const U64* __restrict__ maskT, const U64* __restrict__ validw,
    U64* __restrict__ keepw)
{
  __shared__ U32 sup[MROWS];
  __shared__ U64 vws[NWORD];
  __shared__ U64 kwsh;
  int t = threadIdx.x;                       // 0..511
  int wave = t >> 6, lane = t & 63;
  for (int i = t; i < MROWS; i += 512) sup[i] = 0;
  if (t < NWORD) vws[t] = validw[t];
  U64 low = (lane == 0) ? 0ull : (~0ull >> (64 - lane));
  U64 intra = (wave == 0) ? maskT[lane] : 0ull;   // chunk 0 diagonal word
  __syncthreads();
  for (int c = 0; c < NWORD; ++c) {
    if (wave == 0) {
      // ---- decide (wave-0 local; ballots are per-wave) ----
      U64 vw = vws[c];
      bool alive = (((vw >> lane) & 1ull) != 0ull) && (sup[c * 64 + lane] == 0u);
      U64 aliveW = __ballot(alive);
      bool myconf = alive && ((intra & aliveW & low) != 0ull);
      U64 confW = __ballot(myconf);
      U64 keep = aliveW & ~confW;            // non-conflicted alive are kept
      U64 rem = confW;                       // resolve conflicted ascending
      while (rem) {
        int b = __ffsll((unsigned long long)rem) - 1;
        rem &= rem - 1;
        U64 Z = __ballot((intra & keep & low) == 0ull);
        if ((Z >> b) & 1ull) keep |= (1ull << b);
      }
      if (lane == 0) { keepw[c] = keep; kwsh = keep; }
      if (c + 1 < NWORD)                     // prefetch next diagonal word
        intra = maskT[(size_t)(c + 1) * MROWS + (c + 1) * 64 + lane];
    }
    __syncthreads();                         // kwsh + sup reads ordered
    U64 keep = kwsh;
    if (keep) {                              // block-uniform
      const U64* colp = maskT + (size_t)c * MROWS;
      int base = (c + 1) * 64;
      U64 m[12];                             // 12*512 = 6144 >= max rows
#pragma unroll
      for (int q = 0; q < 12; ++q) {
        int i = base + q * 512 + t;
        int ic = (i > MROWS - 1) ? (MROWS - 1) : i;
        m[q] = colp[ic];
      }
#pragma unroll
      for (int q = 0; q < 12; ++q) {
        int i = base + q * 512 + t;
        if (i < PRE_N && (m[q] & keep)) sup[i] = 1u;
      }
    }
    __syncthreads();                         // sup[] complete before decide c+1
  }
}

// ============================================================================
// K11: proposals: prefix-popcount ranks, first 300 kept boxes, zeros elsewhere
// ============================================================================
__global__ __launch_bounds__(256) void k_out(
    const U64* __restrict__ keepw, const float* __restrict__ sboxes,
    float* __restrict__ prop)
{
  __shared__ U64 kw[NWORD];
  __shared__ U32 pre[NWORD + 1];
  int t = threadIdx.x;
  if (t < NWORD) kw[t] = keepw[t];
  __syncthreads();
  if (t == 0) {
    U32 s = 0;
    for (int w = 0; w < NWORD; ++w) { pre[w] = s; s += (U32)__popcll(kw[w]); }
    pre[NWORD] = s;
  }
  for (int x = t; x < POST_N * 4; x += 256) prop[x] = 0.f;
  __syncthreads();
  for (int i = t; i < PRE_N; i += 256) {
    int w = i >> 6, b = i & 63;
    if ((kw[w] >> b) & 1ull) {
      U64 lowb = (b == 0) ? 0ull : (~0ull >> (64 - b));
      U32 r = pre[w] + (U32)__popcll(kw[w] & lowb);
      if (r < POST_N)
        *(float4*)&prop[(size_t)r*4] = *(const float4*)&sboxes[(size_t)i*4];
    }
  }
}

// ============================================================================
extern "C" void kernel_launch(void* const* d_in, const int* in_sizes, int n_in,
                              void* d_out, int out_size, void* d_ws, size_t ws_size,
                              hipStream_t stream)
{
  (void)in_sizes; (void)n_in; (void)out_size;
  if (ws_size < WS_NEED) return;   // scratch too small; bail safely

  const float* feats = (const float*)d_in[0];
  const float* ancs  = (const float*)d_in[1];
  const float* W_b   = (const float*)d_in[3];
  const float* b_b   = (const float*)d_in[4];
  const float* W_cls = (const float*)d_in[5];
  const float* b_cls = (const float*)d_in[6];
  const float* W_reg = (const float*)d_in[7];
  const float* b_reg = (const float*)d_in[8];

  float* out    = (float*)d_out;
  float* outCls = out;                 // 90000
  float* outReg = out + 90000;         // 360000
  float* prop   = out + 450000;        // 1200

  char* ws = (char*)d_ws;
  float* H      = (float*)(ws + OFF_H);
  float* boxes  = (float*)(ws + OFF_BOXES);
  U32*   keys   = (U32*)  (ws + OFF_KEYS);
  U64*   maskT  = (U64*)  (ws + OFF_MASKT);
  U64*   sel    = (U64*)  (ws + OFF_SEL);
  float* sboxes = (float*)(ws + OFF_SBOX);
  U64*   validw = (U64*)  (ws + OFF_VALIDW);
  U64*   keepw  = (U64*)  (ws + OFF_KEEPW);
  U32*   hist   = (U32*)  (ws + OFF_HIST);
  U32*   cnt    = (U32*)  (ws + OFF_CNT);
  U32*   tiebuf = (U32*)  (ws + OFF_TIE);

  k_gemm1<<<dim3(8, 79), dim3(256), 0, stream>>>(feats, W_b, b_b, H,
                                                 hist, cnt, (U32*)validw);
  k_heads<<<dim3(2500), dim3(256), 0, stream>>>(H, W_cls, b_cls, W_reg, b_reg,
                                                outCls, outReg);
  k_decode<<<dim3(352), dim3(256), 0, stream>>>(outCls, outReg, ancs,
                                                boxes, keys, hist);
  k_scan<<<dim3(1), dim3(256), 0, stream>>>(hist, cnt, 0);
  for (int lv = 1; lv <= 3; ++lv) {
    k_hist<<<dim3(352), dim3(256), 0, stream>>>(keys, hist, cnt, lv);
    k_scan<<<dim3(1), dim3(256), 0, stream>>>(hist, cnt, lv);
  }
  k_compact<<<dim3(352), dim3(256), 0, stream>>>(keys, cnt, sel, tiebuf);
  k_ties<<<dim3(1), dim3(256), 0, stream>>>(cnt, tiebuf, sel);
  k_rank<<<dim3(24), dim3(256), 0, stream>>>(sel, boxes, sboxes, validw);
  k_mask<<<dim3(94, 94), dim3(256), 0, stream>>>(sboxes, maskT);
  k_nms<<<dim3(1), dim3(512), 0, stream>>>(maskT, validw, keepw);
  k_out<<<dim3(1), dim3(256), 0, stream>>>(keepw, sboxes, prop);
}

// Round 14
// 543.979 us; speedup vs baseline: 2.0942x; 1.0025x over previous
//
#include <hip/hip_runtime.h>
#include <math.h>

typedef unsigned int U32;
typedef unsigned long long U64;

#define NBOX   90000
#define NPIX   10000
#define KDIM   1024
#define CBOT   512
#define PRE_N  6000
#define POST_N 300
#define NWORD  94      // ceil(6000/64)
#define MROWS  6016    // 94*64 rows allocated per column in maskT

// ---------------- workspace layout (byte offsets, all 16B aligned) ----------
#define OFF_H       0ULL          // 10000*512*4   = 20480000
#define OFF_BOXES   20480000ULL   // 90000*4*4     = 1440000
#define OFF_KEYS    21920000ULL   // 90000*4       = 360000
#define OFF_MASKT   22280000ULL   // 94*6016*8     = 4524032 (column-major)
#define OFF_SEL     26804032ULL   // 6000*8        = 48000
#define OFF_SBOX    26852032ULL   // 6000*4*4      = 96000
#define OFF_VALIDW  26948032ULL   // 94*8 -> 768
#define OFF_KEEPW   26948800ULL   // 768
#define OFF_HIST    26949568ULL   // 256*4 -> 1024
#define OFF_CNT     26950592ULL   // 64*4  -> 256
#define OFF_TIE     26950848ULL   // 4096*4 = 16384
#define WS_NEED     26967232ULL

// cnt[] slots: 0=prefix/T  1=target_remaining(->need_ties)  2=c_gt  8=n_gt atomic  9=n_tie atomic

// ============================================================================
// K1: h = relu(feats @ W_b + b_b)  fp32, 128x64 tile, 8x4 acc/thread, BK=16.
// R13 counters: FETCH=163MB vs 63MB ideal — dim3(8,79) put each XCD on one
// column-stripe over ALL of A (XCD = linear%8 = x), so every XCD streamed
// 41MB A through its 4MB L2 (328MB misses, L3 absorbed half). This round:
// XCD-aware remap (T1): 1D grid 640, c=bid&7 owns y-rows {c*10+s%10} (5.2MB
// A-slab ~= L2-resident) x all 8 col-blocks (x=s/10). Pure scheduling
// permutation -> H bitwise identical. 8 dead blocks (yy>=79) exit early.
// Also zero-inits hist/cnt/validw (block 0 only).
// ============================================================================
__global__ __launch_bounds__(256, 4) void k_gemm1(
    const float* __restrict__ A, const float* __restrict__ W,
    const float* __restrict__ bias, float* __restrict__ H,
    U32* __restrict__ hist, U32* __restrict__ cnt, U32* __restrict__ validw32)
{
  int t = threadIdx.x;
  if (blockIdx.x == 0) {
    hist[t] = 0;
    if (t < 64)  cnt[t] = (t == 1) ? (U32)PRE_N : 0u;
    if (t < 188) validw32[t] = 0;
  }
  int bid = blockIdx.x;
  int c = bid & 7;                 // XCD under round-robin dispatch
  int s = bid >> 3;                // 0..79
  int x = s / 10;                  // 0..7  column block
  int yy = c * 10 + (s % 10);      // 0..79 row block; XCD-local A slab
  if (yy >= 79) return;            // 8 dead blocks
  __shared__ float As[16][132];   // [k][m], pad: bank stride 4 per k-row
  __shared__ float Bs[16][68];    // [k][n], 64 cols + pad
  int m0 = yy * 128, n0 = x * 64;
  int tm = t >> 4, tn = t & 15;
  int ar = t >> 1, ac = (t & 1) << 3;   // A stage: row ar, cols ac..ac+7
  int bk = t >> 4, bc = (t & 15) << 2;  // B stage: row bk, cols bc..bc+3
  float acc[8][4];
#pragma unroll
  for (int i = 0; i < 8; ++i)
#pragma unroll
    for (int j = 0; j < 4; ++j) acc[i][j] = 0.f;

  // prologue: first tile's loads
  int arow = m0 + ar;
  float4 a0 = make_float4(0.f,0.f,0.f,0.f), a1 = a0;
  if (arow < NPIX) {
    a0 = *(const float4*)&A[(size_t)arow * KDIM + ac];
    a1 = *(const float4*)&A[(size_t)arow * KDIM + ac + 4];
  }
  float4 b0 = *(const float4*)&W[(size_t)bk * CBOT + n0 + bc];

  for (int k0 = 0; k0 < KDIM; k0 += 16) {
    __syncthreads();                 // prior FMA readers done
    As[ac+0][ar] = a0.x; As[ac+1][ar] = a0.y; As[ac+2][ar] = a0.z; As[ac+3][ar] = a0.w;
    As[ac+4][ar] = a1.x; As[ac+5][ar] = a1.y; As[ac+6][ar] = a1.z; As[ac+7][ar] = a1.w;
    *(float4*)&Bs[bk][bc] = b0;
    __syncthreads();
    if (k0 + 16 < KDIM) {            // issue next-tile loads BEFORE FMA loop
      int kn = k0 + 16;
      if (arow < NPIX) {
        a0 = *(const float4*)&A[(size_t)arow * KDIM + kn + ac];
        a1 = *(const float4*)&A[(size_t)arow * KDIM + kn + ac + 4];
      }
      b0 = *(const float4*)&W[(size_t)(kn + bk) * CBOT + n0 + bc];
    }
#pragma unroll
    for (int kk = 0; kk < 16; ++kk) {
      float4 av0 = *(float4*)&As[kk][tm*8];      // 16-lane broadcast, no conflict
      float4 av1 = *(float4*)&As[kk][tm*8+4];
      float4 bv0 = *(float4*)&Bs[kk][tn*4];      // 2-way aliasing: free
      float am[8] = {av0.x,av0.y,av0.z,av0.w,av1.x,av1.y,av1.z,av1.w};
      float bm[4] = {bv0.x,bv0.y,bv0.z,bv0.w};
#pragma unroll
      for (int i = 0; i < 8; ++i)
#pragma unroll
        for (int j = 0; j < 4; ++j)
          acc[i][j] = fmaf(am[i], bm[j], acc[i][j]);
    }
  }
  float4 bb = *(const float4*)&bias[n0 + tn*4];
  float bm[4] = {bb.x, bb.y, bb.z, bb.w};
#pragma unroll
  for (int i = 0; i < 8; ++i) {
    int r = m0 + tm*8 + i;
    if (r < NPIX) {
      float4 o;
      o.x = fmaxf(acc[i][0] + bm[0], 0.f);
      o.y = fmaxf(acc[i][1] + bm[1], 0.f);
      o.z = fmaxf(acc[i][2] + bm[2], 0.f);
      o.w = fmaxf(acc[i][3] + bm[3], 0.f);
      *(float4*)&H[(size_t)r * CBOT + n0 + tn*4] = o;
    }
  }
}

// ============================================================================
// K2: cls = sigmoid(h@W_cls+b_cls), reg = h@W_reg+b_reg  (4 pixels / block)
// ============================================================================
__global__ __launch_bounds__(256) void k_heads(
    const float* __restrict__ H, const float* __restrict__ Wc,
    const float* __restrict__ bc, const float* __restrict__ Wr,
    const float* __restrict__ br, float* __restrict__ outCls,
    float* __restrict__ outReg)
{
  __shared__ float hs[4][516];
  int t = threadIdx.x;
  int p0 = blockIdx.x * 4;
  for (int q = t; q < 512; q += 256) {
    int row = q >> 7, off = (q & 127) << 2;
    *(float4*)&hs[row][off] = *(const float4*)&H[(size_t)(p0 + row) * CBOT + off];
  }
  __syncthreads();
  if (t < 180) {
    int pl = t / 45, c = t % 45;
    const float* wp; int stride; float bval;
    if (c < 9) { wp = Wc + c;       stride = 9;  bval = bc[c]; }
    else       { wp = Wr + (c - 9); stride = 36; bval = br[c - 9]; }
    float s = 0.f;
    const float* hrow = hs[pl];
    for (int k = 0; k < CBOT; k += 4) {
      float4 hv = *(const float4*)&hrow[k];
      s = fmaf(hv.x, wp[(size_t)(k+0)*stride], s);
      s = fmaf(hv.y, wp[(size_t)(k+1)*stride], s);
      s = fmaf(hv.z, wp[(size_t)(k+2)*stride], s);
      s = fmaf(hv.w, wp[(size_t)(k+3)*stride], s);
    }
    s += bval;
    int p = p0 + pl;
    if (c < 9) outCls[(size_t)p*9 + c] = 1.f / (1.f + expf(-s));
    else       outReg[(size_t)p*36 + (c - 9)] = s;
  }
}

// ============================================================================
// K3: decode boxes, size filter, sortable keys, level-0 histogram
// ============================================================================
__global__ __launch_bounds__(256) void k_decode(
    const float* __restrict__ outCls, const float* __restrict__ outReg,
    const float* __restrict__ ancs, float* __restrict__ boxes,
    U32* __restrict__ keys, U32* __restrict__ hist)
{
  __shared__ U32 lh[256];
  int t = threadIdx.x;
  int tid = blockIdx.x * 256 + t;
  lh[t] = 0;
  __syncthreads();
  if (tid < NBOX) {
    float sc = outCls[tid];
    float4 of = *(const float4*)&outReg[(size_t)tid*4];
    float4 an = *(const float4*)&ancs[(size_t)tid*4];
    float cx = an.x + of.x * an.z;
    float cy = an.y + of.y * an.w;
    float ww = an.z * expf(of.z);
    float hh = an.w * expf(of.w);
    float x1 = fminf(fmaxf(cx - ww * 0.5f, 0.f), 1.f);
    float y1 = fminf(fmaxf(cy - hh * 0.5f, 0.f), 1.f);
    float x2 = fminf(fmaxf(cx + ww * 0.5f, 0.f), 1.f);
    float y2 = fminf(fmaxf(cy + hh * 0.5f, 0.f), 1.f);
    bool ok = ((x2 - x1) * 100.f >= 1.f) && ((y2 - y1) * 100.f >= 1.f);
    float msc = ok ? sc : -1.f;
    U32 u = __float_as_uint(msc);
    U32 key = (u & 0x80000000u) ? ~u : (u | 0x80000000u);
    keys[tid] = key;
    *(float4*)&boxes[(size_t)tid*4] = make_float4(x1, y1, x2, y2);
    atomicAdd(&lh[key >> 24], 1u);
  }
  __syncthreads();
  if (lh[t]) atomicAdd(&hist[t], lh[t]);
}

// ============================================================================
// K4: radix-select scan step (one per level). Picks digit, updates prefix /
// remaining target / count-above, zeroes hist for next level.
// ============================================================================
__global__ __launch_bounds__(256) void k_scan(
    U32* __restrict__ hist, U32* __restrict__ cnt, int level)
{
  __shared__ U32 lh[256];
  int t = threadIdx.x;
  lh[t] = hist[t];
  __syncthreads();
  if (t == 0) {
    U32 target = cnt[1];
    U32 cum = 0;
    int d = 255;
    while (d > 0) {
      U32 hh = lh[d];
      if (cum + hh >= target) break;
      cum += hh; --d;
    }
    cnt[0] |= ((U32)d) << (24 - 8*level);
    cnt[1] = target - cum;
    cnt[2] += cum;
  }
  __syncthreads();
  hist[t] = 0;
}

// ============================================================================
// K5: filtered histogram for levels 1..3
// ============================================================================
__global__ __launch_bounds__(256) void k_hist(
    const U32* __restrict__ keys, U32* __restrict__ hist,
    const U32* __restrict__ cnt, int level)
{
  __shared__ U32 lh[256];
  int t = threadIdx.x;
  int tid = blockIdx.x * 256 + t;
  lh[t] = 0;
  __syncthreads();
  if (tid < NBOX) {
    U32 k = keys[tid];
    U32 prefix = cnt[0];
    int shift = 32 - 8*level;
    if ((k >> shift) == (prefix >> shift)) {
      U32 bin = (k >> (24 - 8*level)) & 0xFFu;
      atomicAdd(&lh[bin], 1u);
    }
  }
  __syncthreads();
  if (lh[t]) atomicAdd(&hist[t], lh[t]);
}

// ============================================================================
// K6: compact: keys > T -> sel (unordered; rank pass sorts later);
//     keys == T -> tie buffer.
// ============================================================================
__global__ __launch_bounds__(256) void k_compact(
    const U32* __restrict__ keys, U32* __restrict__ cnt,
    U64* __restrict__ sel, U32* __restrict__ tiebuf)
{
  int tid = blockIdx.x * 256 + threadIdx.x;
  if (tid >= NBOX) return;
  U32 k = keys[tid];
  U32 T = cnt[0];
  if (k > T) {
    U32 p = atomicAdd(&cnt[8], 1u);
    sel[p] = ((U64)k << 32) | (U64)(0xFFFFFFFFu - (U32)tid);
  } else if (k == T) {
    U32 p = atomicAdd(&cnt[9], 1u);
    if (p < 4096) tiebuf[p] = (U32)tid;
  }
}

// ============================================================================
// K7: resolve ==T ties by smallest index (stable top_k semantics)
// ============================================================================
__global__ __launch_bounds__(256) void k_ties(
    U32* __restrict__ cnt, const U32* __restrict__ tiebuf, U64* __restrict__ sel)
{
  __shared__ U32 tb[4096];
  int t = threadIdx.x;
  U32 m = cnt[9]; if (m > 4096u) m = 4096u;
  U32 need = cnt[1];
  U32 cgt  = cnt[2];
  U32 T    = cnt[0];
  for (U32 j = t; j < m; j += 256) tb[j] = tiebuf[j];
  __syncthreads();
  for (U32 x = t; x < m; x += 256) {
    U32 my = tb[x];
    U32 r = 0;
    for (U32 j = 0; j < m; ++j) r += (tb[j] < my) ? 1u : 0u;
    if (r < need) sel[cgt + r] = ((U64)T << 32) | (U64)(0xFFFFFFFFu - my);
  }
}

// ============================================================================
// K8: exact rank of each selected element (score desc, idx asc) -> sorted
// boxes + packed valid bits. 36M u64 compares, LDS-staged. Order-invariant
// wrt sel's (atomic-nondeterministic) storage order.
// ============================================================================
__global__ __launch_bounds__(256) void k_rank(
    const U64* __restrict__ sel, const float* __restrict__ boxes,
    float* __restrict__ sboxes, U64* __restrict__ validw)
{
  __shared__ U64 ss[PRE_N];
  int t = threadIdx.x;
  for (int j = t; j < PRE_N; j += 256) ss[j] = sel[j];
  __syncthreads();
  int i = blockIdx.x * 256 + t;
  if (i >= PRE_N) return;
  U64 C = ss[i];
  int r = 0;
  for (int j = 0; j < PRE_N; ++j) r += (ss[j] > C) ? 1 : 0;
  U32 key = (U32)(C >> 32);
  U32 idx = 0xFFFFFFFFu - (U32)(C & 0xFFFFFFFFull);
  *(float4*)&sboxes[(size_t)r*4] = *(const float4*)&boxes[(size_t)idx*4];
  if (key & 0x80000000u)
    atomicOr(&validw[r >> 6], 1ull << (r & 63));
}

// ============================================================================
// K9: IoU > 0.7 bitmask, COLUMN-word-major: maskT[cw*MROWS + i] bit x =
//     iou(row i, box cw*64+x) > thr. Upper triangle + diagonal only (NMS
//     reads only i >= cw*64). Rows 6000..6015 in touched blocks written as 0.
// ============================================================================
__global__ __launch_bounds__(256) void k_mask(
    const float* __restrict__ sboxes, U64* __restrict__ maskT)
{
  int cw = blockIdx.x, rg = blockIdx.y;
  if (rg < cw) return;                       // lower triangle unused by NMS
  int t = threadIdx.x;
  int lane = t & 63, wv = t >> 6;
  int col = cw * 64 + lane;
  int cc = (col < PRE_N) ? col : (PRE_N - 1);
  float4 cb = *(const float4*)&sboxes[(size_t)cc*4];
  float areaC = (cb.z - cb.x) * (cb.w - cb.y);
  bool colok = (col < PRE_N);
  for (int rr = wv; rr < 64; rr += 4) {
    int row = rg * 64 + rr;
    U64 word = 0;
    if (row < PRE_N) {
      float4 rb = *(const float4*)&sboxes[(size_t)row*4];
      float areaR = (rb.z - rb.x) * (rb.w - rb.y);
      float ix1 = fmaxf(rb.x, cb.x), iy1 = fmaxf(rb.y, cb.y);
      float ix2 = fminf(rb.z, cb.z), iy2 = fminf(rb.w, cb.w);
      float inter = fmaxf(ix2 - ix1, 0.f) * fmaxf(iy2 - iy1, 0.f);
      float uni = areaR + areaC - inter;
      float iou = inter / fmaxf(uni, 1e-9f);
      word = __ballot(colok && (iou > 0.7f));
    }
    if (lane == 0) maskT[(size_t)cw * MROWS + row] = word;
  }
}

// ============================================================================
// K10: sequential-equivalent NMS — 8 WAVES (512 threads), strict barrier
// phases (R13 WIN: 210us -> out of top-5). Wave 0 decides chunk c; barrier;
// all 512 lanes apply suppression; barrier. Bitwise-deterministic.
// ============================================================================
__global__ __launch_bounds__(512, 1) void k_nms(
    const U64* __restrict__ maskT, const U64* __restrict__ validw,
    U64* __restrict__ keepw)
{
  __shared__ U32 sup[MROWS];
  __shared__ U64 vws[NWORD];
  __shared__ U64 kwsh;
  int t = threadIdx.x;                       // 0..511
  int wave = t >> 6, lane = t & 63;
  for (int i = t; i < MROWS; i += 512) sup[i] = 0;
  if (t < NWORD) vws[t] = validw[t];
  U64 low = (lane == 0) ? 0ull : (~0ull >> (64 - lane));
  U64 intra = (wave == 0) ? maskT[lane] : 0ull;   // chunk 0 diagonal word
  __syncthreads();
  for (int c = 0; c < NWORD; ++c) {
    if (wave == 0) {
      // ---- decide (wave-0 local; ballots are per-wave) ----
      U64 vw = vws[c];
      bool alive = (((vw >> lane) & 1ull) != 0ull) && (sup[c * 64 + lane] == 0u);
      U64 aliveW = __ballot(alive);
      bool myconf = alive && ((intra & aliveW & low) != 0ull);
      U64 confW = __ballot(myconf);
      U64 keep = aliveW & ~confW;            // non-conflicted alive are kept
      U64 rem = confW;                       // resolve conflicted ascending
      while (rem) {
        int b = __ffsll((unsigned long long)rem) - 1;
        rem &= rem - 1;
        U64 Z = __ballot((intra & keep & low) == 0ull);
        if ((Z >> b) & 1ull) keep |= (1ull << b);
      }
      if (lane == 0) { keepw[c] = keep; kwsh = keep; }
      if (c + 1 < NWORD)                     // prefetch next diagonal word
        intra = maskT[(size_t)(c + 1) * MROWS + (c + 1) * 64 + lane];
    }
    __syncthreads();                         // kwsh + sup reads ordered
    U64 keep = kwsh;
    if (keep) {                              // block-uniform
      const U64* colp = maskT + (size_t)c * MROWS;
      int base = (c + 1) * 64;
      U64 m[12];                             // 12*512 = 6144 >= max rows
#pragma unroll
      for (int q = 0; q < 12; ++q) {
        int i = base + q * 512 + t;
        int ic = (i > MROWS - 1) ? (MROWS - 1) : i;
        m[q] = colp[ic];
      }
#pragma unroll
      for (int q = 0; q < 12; ++q) {
        int i = base + q * 512 + t;
        if (i < PRE_N && (m[q] & keep)) sup[i] = 1u;
      }
    }
    __syncthreads();                         // sup[] complete before decide c+1
  }
}

// ============================================================================
// K11: proposals: prefix-popcount ranks, first 300 kept boxes, zeros elsewhere
// ============================================================================
__global__ __launch_bounds__(256) void k_out(
    const U64* __restrict__ keepw, const float* __restrict__ sboxes,
    float* __restrict__ prop)
{
  __shared__ U64 kw[NWORD];
  __shared__ U32 pre[NWORD + 1];
  int t = threadIdx.x;
  if (t < NWORD) kw[t] = keepw[t];
  __syncthreads();
  if (t == 0) {
    U32 s = 0;
    for (int w = 0; w < NWORD; ++w) { pre[w] = s; s += (U32)__popcll(kw[w]); }
    pre[NWORD] = s;
  }
  for (int x = t; x < POST_N * 4; x += 256) prop[x] = 0.f;
  __syncthreads();
  for (int i = t; i < PRE_N; i += 256) {
    int w = i >> 6, b = i & 63;
    if ((kw[w] >> b) & 1ull) {
      U64 lowb = (b == 0) ? 0ull : (~0ull >> (64 - b));
      U32 r = pre[w] + (U32)__popcll(kw[w] & lowb);
      if (r < POST_N)
        *(float4*)&prop[(size_t)r*4] = *(const float4*)&sboxes[(size_t)i*4];
    }
  }
}

// ============================================================================
extern "C" void kernel_launch(void* const* d_in, const int* in_sizes, int n_in,
                              void* d_out, int out_size, void* d_ws, size_t ws_size,
                              hipStream_t stream)
{
  (void)in_sizes; (void)n_in; (void)out_size;
  if (ws_size < WS_NEED) return;   // scratch too small; bail safely

  const float* feats = (const float*)d_in[0];
  const float* ancs  = (const float*)d_in[1];
  const float* W_b   = (const float*)d_in[3];
  const float* b_b   = (const float*)d_in[4];
  const float* W_cls = (const float*)d_in[5];
  const float* b_cls = (const float*)d_in[6];
  const float* W_reg = (const float*)d_in[7];
  const float* b_reg = (const float*)d_in[8];

  float* out    = (float*)d_out;
  float* outCls = out;                 // 90000
  float* outReg = out + 90000;         // 360000
  float* prop   = out + 450000;        // 1200

  char* ws = (char*)d_ws;
  float* H      = (float*)(ws + OFF_H);
  float* boxes  = (float*)(ws + OFF_BOXES);
  U32*   keys   = (U32*)  (ws + OFF_KEYS);
  U64*   maskT  = (U64*)  (ws + OFF_MASKT);
  U64*   sel    = (U64*)  (ws + OFF_SEL);
  float* sboxes = (float*)(ws + OFF_SBOX);
  U64*   validw = (U64*)  (ws + OFF_VALIDW);
  U64*   keepw  = (U64*)  (ws + OFF_KEEPW);
  U32*   hist   = (U32*)  (ws + OFF_HIST);
  U32*   cnt    = (U32*)  (ws + OFF_CNT);
  U32*   tiebuf = (U32*)  (ws + OFF_TIE);

  k_gemm1<<<dim3(640), dim3(256), 0, stream>>>(feats, W_b, b_b, H,
                                               hist, cnt, (U32*)validw);
  k_heads<<<dim3(2500), dim3(256), 0, stream>>>(H, W_cls, b_cls, W_reg, b_reg,
                                                outCls, outReg);
  k_decode<<<dim3(352), dim3(256), 0, stream>>>(outCls, outReg, ancs,
                                                boxes, keys, hist);
  k_scan<<<dim3(1), dim3(256), 0, stream>>>(hist, cnt, 0);
  for (int lv = 1; lv <= 3; ++lv) {
    k_hist<<<dim3(352), dim3(256), 0, stream>>>(keys, hist, cnt, lv);
    k_scan<<<dim3(1), dim3(256), 0, stream>>>(hist, cnt, lv);
  }
  k_compact<<<dim3(352), dim3(256), 0, stream>>>(keys, cnt, sel, tiebuf);
  k_ties<<<dim3(1), dim3(256), 0, stream>>>(cnt, tiebuf, sel);
  k_rank<<<dim3(24), dim3(256), 0, stream>>>(sel, boxes, sboxes, validw);
  k_mask<<<dim3(94, 94), dim3(256), 0, stream>>>(sboxes, maskT);
  k_nms<<<dim3(1), dim3(512), 0, stream>>>(maskT, validw, keepw);
  k_out<<<dim3(1), dim3(256), 0, stream>>>(keepw, sboxes, prop);
}